// Round 4
// baseline (1253.811 us; speedup 1.0000x reference)
//
#include <hip/hip_runtime.h>
#include <hip/hip_fp16.h>
#include <math.h>

#define TEMPERATURE 0.07f

// ---------------- ws layout (float offsets) ----------------
#define WS_COST   0          // 128*128*128 = 2097152
#define WS_SIM    2097152    // 16384
#define WS_IVG    2113536    // 128
#define WS_ITG    2113664    // 128
#define WS_IVV    2113792    // 16384
#define WS_IVT    2130176    // 16384
#define WS_COLS   2146560    // 16384 ints
#define WS_ACC    2162944    // 16 floats

// ---------------- init: zero accumulators ----------------
__global__ void k_init(float* acc) {
    if (threadIdx.x < 16) acc[threadIdx.x] = 0.0f;
}

// ---------------- row inverse norms: x [rows][1024] ----------------
__global__ __launch_bounds__(256) void k_invnorm(const float* __restrict__ x,
                                                 float* __restrict__ out, int rows) {
    int wid = threadIdx.x >> 6;
    int lane = threadIdx.x & 63;
    int row = blockIdx.x * 4 + wid;
    if (row >= rows) return;
    const float* xr = x + (size_t)row * 1024;
    float s = 0.0f;
#pragma unroll
    for (int i = 0; i < 4; i++) {
        float4 v = *(const float4*)&xr[i * 256 + lane * 4];
        s += v.x * v.x + v.y * v.y + v.z * v.z + v.w * v.w;
    }
#pragma unroll
    for (int off = 32; off > 0; off >>= 1) s += __shfl_xor(s, off);
    if (lane == 0) out[row] = 1.0f / fmaxf(sqrtf(s), 1e-12f);
}

// ---------------- sim[i][j] = dot(v_g[i], t_g[j]) * iv[i]*it[j] / TEMP ----------------
__global__ __launch_bounds__(128) void k_sim(const float* __restrict__ vg,
                                             const float* __restrict__ tg,
                                             const float* __restrict__ ivg,
                                             const float* __restrict__ itg,
                                             float* __restrict__ sim) {
    int i = blockIdx.x, j = threadIdx.x;
    const float* vr = vg + (size_t)i * 1024;
    const float* tr = tg + (size_t)j * 1024;
    float acc = 0.0f;
    for (int k = 0; k < 1024; k += 4) {
        float4 a = *(const float4*)&vr[k];
        float4 b = *(const float4*)&tr[k];
        acc += a.x * b.x + a.y * b.y + a.z * b.z + a.w * b.w;
    }
    sim[i * 128 + j] = acc * ivg[i] * itg[j] / TEMPERATURE;
}

// ---------------- L_global from sim (single block, 128 threads) ----------------
__global__ __launch_bounds__(128) void k_global(const float* __restrict__ sim,
                                                float* __restrict__ acc) {
    __shared__ float red[128];
    int t = threadIdx.x;
    float m = -3e38f, m2 = -3e38f;
    for (int j = 0; j < 128; j++) {
        m = fmaxf(m, sim[t * 128 + j]);
        m2 = fmaxf(m2, sim[j * 128 + t]);
    }
    float s = 0.0f, s2 = 0.0f;
    for (int j = 0; j < 128; j++) {
        s += expf(sim[t * 128 + j] - m);
        s2 += expf(sim[j * 128 + t] - m2);
    }
    float contrib = 2.0f * sim[t * 128 + t] - (m + logf(s)) - (m2 + logf(s2));
    red[t] = contrib;
    __syncthreads();
    for (int o = 64; o > 0; o >>= 1) {
        if (t < o) red[t] += red[t + o];
        __syncthreads();
    }
    if (t == 0) acc[0] = -red[0] / 256.0f;   // 0.5*(mean+mean), negated
}

// ---------------- cost[b][n][m] = 1 - cos(V[b,n], T[b,m]) ----------------
__global__ __launch_bounds__(256) void k_cost(const float* __restrict__ V,
                                              const float* __restrict__ T,
                                              const float* __restrict__ ivv,
                                              const float* __restrict__ ivt,
                                              float* __restrict__ cost) {
    __shared__ float As[16][68];
    __shared__ float Bs[16][68];
    int b = blockIdx.x >> 2;
    int tile = blockIdx.x & 3;
    int n0 = (tile >> 1) * 64, m0 = (tile & 1) * 64;
    int t = threadIdx.x;
    int lr = t >> 2;
    int lq = t & 3;
    int tm = t >> 4;
    int tn = t & 15;
    const float* Vb = V + (size_t)b * 128 * 1024;
    const float* Tb = T + (size_t)b * 128 * 1024;
    float acc[4][4];
#pragma unroll
    for (int i = 0; i < 4; i++)
#pragma unroll
        for (int j = 0; j < 4; j++) acc[i][j] = 0.0f;

    for (int k0 = 0; k0 < 1024; k0 += 16) {
        float4 av = *(const float4*)&Vb[(size_t)(n0 + lr) * 1024 + k0 + lq * 4];
        float4 bv = *(const float4*)&Tb[(size_t)(m0 + lr) * 1024 + k0 + lq * 4];
        __syncthreads();
        As[lq * 4 + 0][lr] = av.x; As[lq * 4 + 1][lr] = av.y;
        As[lq * 4 + 2][lr] = av.z; As[lq * 4 + 3][lr] = av.w;
        Bs[lq * 4 + 0][lr] = bv.x; Bs[lq * 4 + 1][lr] = bv.y;
        Bs[lq * 4 + 2][lr] = bv.z; Bs[lq * 4 + 3][lr] = bv.w;
        __syncthreads();
#pragma unroll
        for (int k = 0; k < 16; k++) {
            float4 a = *(const float4*)&As[k][tm * 4];
            float4 q = *(const float4*)&Bs[k][tn * 4];
            acc[0][0] += a.x * q.x; acc[0][1] += a.x * q.y; acc[0][2] += a.x * q.z; acc[0][3] += a.x * q.w;
            acc[1][0] += a.y * q.x; acc[1][1] += a.y * q.y; acc[1][2] += a.y * q.z; acc[1][3] += a.y * q.w;
            acc[2][0] += a.z * q.x; acc[2][1] += a.z * q.y; acc[2][2] += a.z * q.z; acc[2][3] += a.z * q.w;
            acc[3][0] += a.w * q.x; acc[3][1] += a.w * q.y; acc[3][2] += a.w * q.z; acc[3][3] += a.w * q.w;
        }
    }
    int nb = n0 + tm * 4, mb = m0 + tn * 4;
    float im[4];
#pragma unroll
    for (int j = 0; j < 4; j++) im[j] = ivt[b * 128 + mb + j];
#pragma unroll
    for (int i = 0; i < 4; i++) {
        float in_ = ivv[b * 128 + nb + i];
        float4 o;
        o.x = 1.0f - acc[i][0] * in_ * im[0];
        o.y = 1.0f - acc[i][1] * in_ * im[1];
        o.z = 1.0f - acc[i][2] * in_ * im[2];
        o.w = 1.0f - acc[i][3] * in_ * im[3];
        *(float4*)&cost[((size_t)b * 128 + nb + i) * 128 + mb] = o;
    }
}

// ================= Hungarian (JV), 2 problems interleaved per wave =============
// Software-pipelined: each problem's next LDS row read + u[i0] readlane are
// issued INSIDE the step as soon as the next row is known, so the read ages
// across the other problem's entire step (~150 cy > ~120 cy LDS latency).
#define HUNG_INF 3.0e38f

__device__ __forceinline__ int rdlane_i(int v, int l) {
    return __builtin_amdgcn_readlane(v, l);
}
__device__ __forceinline__ float rdlane_f(float v, int l) {
    return __int_as_float(__builtin_amdgcn_readlane(__float_as_int(v), l));
}

// full-wave u32 min via DPP (identity UINT_MAX); result valid in lane 63
__device__ __forceinline__ unsigned int dpp_umin_wave(unsigned int x) {
    int o;
    o = __builtin_amdgcn_update_dpp(-1, (int)x, 0x111, 0xF, 0xF, false); // row_shr:1
    x = (x < (unsigned int)o) ? x : (unsigned int)o;
    o = __builtin_amdgcn_update_dpp(-1, (int)x, 0x112, 0xF, 0xF, false); // row_shr:2
    x = (x < (unsigned int)o) ? x : (unsigned int)o;
    o = __builtin_amdgcn_update_dpp(-1, (int)x, 0x114, 0xF, 0xF, false); // row_shr:4
    x = (x < (unsigned int)o) ? x : (unsigned int)o;
    o = __builtin_amdgcn_update_dpp(-1, (int)x, 0x118, 0xF, 0xF, false); // row_shr:8
    x = (x < (unsigned int)o) ? x : (unsigned int)o;
    o = __builtin_amdgcn_update_dpp(-1, (int)x, 0x142, 0xF, 0xF, false); // row_bcast:15
    x = (x < (unsigned int)o) ? x : (unsigned int)o;
    o = __builtin_amdgcn_update_dpp(-1, (int)x, 0x143, 0xF, 0xF, false); // row_bcast:31
    x = (x < (unsigned int)o) ? x : (unsigned int)o;
    return x;
}

__device__ __forceinline__ unsigned int pack_h2(float a, float b) {
    unsigned int ua = (unsigned int)__half_as_ushort(__float2half(a));
    unsigned int ub = (unsigned int)__half_as_ushort(__float2half(b));
    return ua | (ub << 16);
}
__device__ __forceinline__ float h2_lo(unsigned int u) {
    return __half2float(__ushort_as_half((unsigned short)(u & 0xFFFFu)));
}
__device__ __forceinline__ float h2_hi(unsigned int u) {
    return __half2float(__ushort_as_half((unsigned short)(u >> 16)));
}

struct JV {
    float v0, v1, u0, u1;      // duals (lane-owned: cols/rows lane, lane+64)
    float minv0, minv1;
    float ui;                  // prefetched u[i0] (wave-uniform)
    unsigned int pk;           // prefetched half2 cost word of row i0 at this lane
    int way0, way1;
    int p0, p1;                // row matched to col lane / lane+64 (-1 none)
    bool used0, used1, intree0, intree1;
    int row;                   // uniform: current outer row
    int i0;                    // uniform: row to expand this tick
    int j0;                    // uniform: column whose matched row is expanding (128=root)
    int cnt;                   // uniform guard
    bool done;
};

__device__ __forceinline__ void jv_newrow(JV& s, const unsigned int* __restrict__ P,
                                          int lane) {
    s.minv0 = s.minv1 = HUNG_INF;
    s.way0 = s.way1 = 128;
    s.used0 = s.used1 = false;
    s.intree0 = (s.row < 64) && (lane == s.row);
    s.intree1 = (s.row >= 64) && (lane == s.row - 64);
    s.j0 = 128;
    s.i0 = s.row;
    s.cnt = 0;
    s.ui = rdlane_f(s.row >= 64 ? s.u1 : s.u0, s.row & 63);
    s.pk = P[s.row * 64 + lane];          // prefetch root row
}

__device__ __forceinline__ void jv_init(JV& s, const unsigned int* __restrict__ P,
                                        int lane) {
    s.v0 = s.v1 = s.u0 = s.u1 = 0.0f;
    s.p0 = s.p1 = -1;
    s.row = 0;
    s.done = false;
    jv_newrow(s, P, lane);
}

// one inner-Dijkstra step; consumes s.pk / s.ui prefetched by the previous step
__device__ __forceinline__ void jv_step(JV& s, const unsigned int* __restrict__ P,
                                        int lane) {
    float c0 = h2_lo(s.pk);
    float c1 = h2_hi(s.pk);
    float cur0 = c0 - s.ui - s.v0;
    float cur1 = c1 - s.ui - s.v1;
    if (!s.used0 && cur0 < s.minv0) { s.minv0 = cur0; s.way0 = s.j0; }
    if (!s.used1 && cur1 < s.minv1) { s.minv1 = cur1; s.way1 = s.j0; }
    float cand0 = s.used0 ? HUNG_INF : s.minv0;
    float cand1 = s.used1 ? HUNG_INF : s.minv1;
    // sortable key: biased value bits (top 25) | column index (low 7).
    unsigned int k0 = (__float_as_uint(cand0 + 1.0f) & 0xFFFFFF80u) | (unsigned int)lane;
    unsigned int k1 = (__float_as_uint(cand1 + 1.0f) & 0xFFFFFF80u) | (unsigned int)(lane + 64);
    unsigned int k = (k0 < k1) ? k0 : k1;
    k = dpp_umin_wave(k);
    unsigned int kmin = (unsigned int)rdlane_i((int)k, 63);
    int j1 = (int)(kmin & 127u);
    float delta = __uint_as_float(kmin & 0xFFFFFF80u) - 1.0f;   // <= exact min, err < 4e-5
    if (s.used0) s.v0 -= delta; else s.minv0 -= delta;
    if (s.used1) s.v1 -= delta; else s.minv1 -= delta;
    if (s.intree0) s.u0 += delta;
    if (s.intree1) s.u1 += delta;
    int pj = rdlane_i(j1 >= 64 ? s.p1 : s.p0, j1 & 63);
    if (pj >= 0 && ++s.cnt <= 200) {
        // column j1 joins tree; its matched row pj expands next.
        if (lane == (j1 & 63)) { if (j1 >= 64) s.used1 = true; else s.used0 = true; }
        if (lane == (pj & 63)) { if (pj < 64) s.intree0 = true; else s.intree1 = true; }
        s.j0 = j1;
        s.i0 = pj;
        // PREFETCH for the next step. Safe: u[pj] cannot change before next step
        // (pj just joined the tree, so it did not receive this step's delta, and
        // duals only change inside steps of THIS problem).
        s.ui = rdlane_f(pj >= 64 ? s.u1 : s.u0, pj & 63);
        s.pk = P[pj * 64 + lane];
    } else {
        // augment along alternating path from j1
        int j = j1;
        while (j != 128) {
            int w = rdlane_i(j >= 64 ? s.way1 : s.way0, j & 63);
            int pw = (w == 128) ? s.row : rdlane_i(w >= 64 ? s.p1 : s.p0, w & 63);
            if (lane == (j & 63)) { if (j >= 64) s.p1 = pw; else s.p0 = pw; }
            j = w;
        }
        s.row++;
        if (s.row < 128) jv_newrow(s, P, lane);
        else s.done = true;
    }
}

// one wave solves TWO batch problems, interleaved to overlap LDS latency.
__global__ __launch_bounds__(64) void k_hungarian(const float* __restrict__ cost,
                                                  int* __restrict__ cols) {
    __shared__ unsigned int PA[128 * 64];   // 32 KB: half2(C[i][l], C[i][l+64])
    __shared__ unsigned int PB[128 * 64];   // 32 KB
    int pr = blockIdx.x;                    // pair index 0..63
    int bA = pr * 2, bB = pr * 2 + 1;
    int lane = threadIdx.x;
    const float* CA = cost + (size_t)bA * 16384;
    const float* CB = cost + (size_t)bB * 16384;
#pragma unroll 4
    for (int r = 0; r < 128; ++r) {
        PA[r * 64 + lane] = pack_h2(CA[r * 128 + lane], CA[r * 128 + 64 + lane]);
        PB[r * 64 + lane] = pack_h2(CB[r * 128 + lane], CB[r * 128 + 64 + lane]);
    }
    __syncthreads();

    JV A, B;
    jv_init(A, PA, lane);
    jv_init(B, PB, lane);
    while (!(A.done && B.done)) {
        if (!A.done) jv_step(A, PA, lane);
        if (!B.done) jv_step(B, PB, lane);
    }
    if (A.p0 >= 0) cols[bA * 128 + A.p0] = lane;
    if (A.p1 >= 0) cols[bA * 128 + A.p1] = lane + 64;
    if (B.p0 >= 0) cols[bB * 128 + B.p0] = lane;
    if (B.p1 >= 0) cols[bB * 128 + B.p1] = lane + 64;
}

// ---------------- node MSE: one block per (b,n) row ----------------
__global__ __launch_bounds__(256) void k_node(const float* __restrict__ V,
                                              const float* __restrict__ T,
                                              const int* __restrict__ cols,
                                              float* __restrict__ acc) {
    int bn = blockIdx.x;
    int b = bn >> 7, n = bn & 127;
    int c = cols[bn];
    const float* vr = V + ((size_t)b * 128 + n) * 1024;
    const float* tr = T + ((size_t)b * 128 + c) * 1024;
    int t = threadIdx.x;
    float4 a = *(const float4*)&vr[t * 4];
    float4 bb = *(const float4*)&tr[t * 4];
    float dx = a.x - bb.x, dy = a.y - bb.y, dz = a.z - bb.z, dw = a.w - bb.w;
    float s = dx * dx + dy * dy + dz * dz + dw * dw;
#pragma unroll
    for (int off = 32; off > 0; off >>= 1) s += __shfl_xor(s, off);
    __shared__ float wsum[4];
    if ((t & 63) == 0) wsum[t >> 6] = s;
    __syncthreads();
    if (t == 0) atomicAdd(&acc[1], wsum[0] + wsum[1] + wsum[2] + wsum[3]);
}

// ---------------- graph MSE ----------------
__global__ __launch_bounds__(256) void k_graph(const float* __restrict__ Av,
                                               const float* __restrict__ At,
                                               float* __restrict__ acc) {
    size_t idx = ((size_t)blockIdx.x * 256 + threadIdx.x) * 4;
    float4 a = *(const float4*)&Av[idx];
    float4 bb = *(const float4*)&At[idx];
    float dx = a.x - bb.x, dy = a.y - bb.y, dz = a.z - bb.z, dw = a.w - bb.w;
    float s = dx * dx + dy * dy + dz * dz + dw * dw;
#pragma unroll
    for (int off = 32; off > 0; off >>= 1) s += __shfl_xor(s, off);
    __shared__ float wsum[4];
    int t = threadIdx.x;
    if ((t & 63) == 0) wsum[t >> 6] = s;
    __syncthreads();
    if (t == 0) atomicAdd(&acc[2], wsum[0] + wsum[1] + wsum[2] + wsum[3]);
}

// ---------------- finalize ----------------
__global__ void k_final(const float* __restrict__ acc, float* __restrict__ out) {
    float lg = acc[0];
    float ln = acc[1] / 16777216.0f;   // 128*128*1024
    float lgr = acc[2] / 2097152.0f;   // 128*128*128
    out[0] = lg + ln + lgr;
    out[1] = lg;
    out[2] = ln;
    out[3] = lgr;
}

extern "C" void kernel_launch(void* const* d_in, const int* in_sizes, int n_in,
                              void* d_out, int out_size, void* d_ws, size_t ws_size,
                              hipStream_t stream) {
    const float* vg = (const float*)d_in[0];
    const float* tg = (const float*)d_in[1];
    const float* V  = (const float*)d_in[2];
    const float* T  = (const float*)d_in[3];
    const float* Av = (const float*)d_in[4];
    const float* At = (const float*)d_in[5];
    float* out = (float*)d_out;
    float* ws = (float*)d_ws;

    float* cost = ws + WS_COST;
    float* sim  = ws + WS_SIM;
    float* ivg  = ws + WS_IVG;
    float* itg  = ws + WS_ITG;
    float* ivv  = ws + WS_IVV;
    float* ivt  = ws + WS_IVT;
    int*   cols = (int*)(ws + WS_COLS);
    float* acc  = ws + WS_ACC;

    k_init<<<1, 16, 0, stream>>>(acc);

    k_invnorm<<<32, 256, 0, stream>>>(vg, ivg, 128);
    k_invnorm<<<32, 256, 0, stream>>>(tg, itg, 128);
    k_invnorm<<<4096, 256, 0, stream>>>(V, ivv, 16384);
    k_invnorm<<<4096, 256, 0, stream>>>(T, ivt, 16384);

    k_sim<<<128, 128, 0, stream>>>(vg, tg, ivg, itg, sim);
    k_global<<<1, 128, 0, stream>>>(sim, acc);

    k_cost<<<512, 256, 0, stream>>>(V, T, ivv, ivt, cost);
    k_hungarian<<<64, 64, 0, stream>>>(cost, cols);

    k_node<<<16384, 256, 0, stream>>>(V, T, cols, acc);
    k_graph<<<2048, 256, 0, stream>>>(Av, At, acc);

    k_final<<<1, 1, 0, stream>>>(acc, out);
}

// Round 5
// 700.425 us; speedup vs baseline: 1.7901x; 1.7901x over previous
//
#include <hip/hip_runtime.h>
#include <hip/hip_fp16.h>
#include <math.h>

#define TEMPERATURE 0.07f

// ---------------- ws layout (float offsets) ----------------
#define WS_COST   0          // 128*128*128 = 2097152
#define WS_SIM    2097152    // 16384
#define WS_IVG    2113536    // 128
#define WS_ITG    2113664    // 128
#define WS_IVV    2113792    // 16384
#define WS_IVT    2130176    // 16384
#define WS_COLS   2146560    // 16384 ints
#define WS_ACC    2162944    // 16 floats

// ---------------- init: zero accumulators ----------------
__global__ void k_init(float* acc) {
    if (threadIdx.x < 16) acc[threadIdx.x] = 0.0f;
}

// ---------------- row inverse norms: x [rows][1024] ----------------
__global__ __launch_bounds__(256) void k_invnorm(const float* __restrict__ x,
                                                 float* __restrict__ out, int rows) {
    int wid = threadIdx.x >> 6;
    int lane = threadIdx.x & 63;
    int row = blockIdx.x * 4 + wid;
    if (row >= rows) return;
    const float* xr = x + (size_t)row * 1024;
    float s = 0.0f;
#pragma unroll
    for (int i = 0; i < 4; i++) {
        float4 v = *(const float4*)&xr[i * 256 + lane * 4];
        s += v.x * v.x + v.y * v.y + v.z * v.z + v.w * v.w;
    }
#pragma unroll
    for (int off = 32; off > 0; off >>= 1) s += __shfl_xor(s, off);
    if (lane == 0) out[row] = 1.0f / fmaxf(sqrtf(s), 1e-12f);
}

// ---------------- sim[i][j] = dot(v_g[i], t_g[j]) * iv[i]*it[j] / TEMP ----------------
__global__ __launch_bounds__(128) void k_sim(const float* __restrict__ vg,
                                             const float* __restrict__ tg,
                                             const float* __restrict__ ivg,
                                             const float* __restrict__ itg,
                                             float* __restrict__ sim) {
    int i = blockIdx.x, j = threadIdx.x;
    const float* vr = vg + (size_t)i * 1024;
    const float* tr = tg + (size_t)j * 1024;
    float acc = 0.0f;
    for (int k = 0; k < 1024; k += 4) {
        float4 a = *(const float4*)&vr[k];
        float4 b = *(const float4*)&tr[k];
        acc += a.x * b.x + a.y * b.y + a.z * b.z + a.w * b.w;
    }
    sim[i * 128 + j] = acc * ivg[i] * itg[j] / TEMPERATURE;
}

// ---------------- L_global from sim (single block, 128 threads) ----------------
__global__ __launch_bounds__(128) void k_global(const float* __restrict__ sim,
                                                float* __restrict__ acc) {
    __shared__ float S[128 * 128];   // 64 KB: stage sim once, coalesced
    __shared__ float red[128];
    int t = threadIdx.x;
    for (int i = t * 4; i < 16384; i += 512)
        *(float4*)&S[i] = *(const float4*)&sim[i];
    __syncthreads();
    float m = -3e38f, m2 = -3e38f;
    for (int j = 0; j < 128; j++) {
        m = fmaxf(m, S[t * 128 + j]);
        m2 = fmaxf(m2, S[j * 128 + t]);
    }
    float s = 0.0f, s2 = 0.0f;
    for (int j = 0; j < 128; j++) {
        s += expf(S[t * 128 + j] - m);
        s2 += expf(S[j * 128 + t] - m2);
    }
    float contrib = 2.0f * S[t * 128 + t] - (m + logf(s)) - (m2 + logf(s2));
    red[t] = contrib;
    __syncthreads();
    for (int o = 64; o > 0; o >>= 1) {
        if (t < o) red[t] += red[t + o];
        __syncthreads();
    }
    if (t == 0) acc[0] = -red[0] / 256.0f;   // 0.5*(mean+mean), negated
}

// ---------------- cost[b][n][m] = 1 - cos(V[b,n], T[b,m]) ----------------
__global__ __launch_bounds__(256) void k_cost(const float* __restrict__ V,
                                              const float* __restrict__ T,
                                              const float* __restrict__ ivv,
                                              const float* __restrict__ ivt,
                                              float* __restrict__ cost) {
    __shared__ float As[16][68];
    __shared__ float Bs[16][68];
    int b = blockIdx.x >> 2;
    int tile = blockIdx.x & 3;
    int n0 = (tile >> 1) * 64, m0 = (tile & 1) * 64;
    int t = threadIdx.x;
    int lr = t >> 2;
    int lq = t & 3;
    int tm = t >> 4;
    int tn = t & 15;
    const float* Vb = V + (size_t)b * 128 * 1024;
    const float* Tb = T + (size_t)b * 128 * 1024;
    float acc[4][4];
#pragma unroll
    for (int i = 0; i < 4; i++)
#pragma unroll
        for (int j = 0; j < 4; j++) acc[i][j] = 0.0f;

    for (int k0 = 0; k0 < 1024; k0 += 16) {
        float4 av = *(const float4*)&Vb[(size_t)(n0 + lr) * 1024 + k0 + lq * 4];
        float4 bv = *(const float4*)&Tb[(size_t)(m0 + lr) * 1024 + k0 + lq * 4];
        __syncthreads();
        As[lq * 4 + 0][lr] = av.x; As[lq * 4 + 1][lr] = av.y;
        As[lq * 4 + 2][lr] = av.z; As[lq * 4 + 3][lr] = av.w;
        Bs[lq * 4 + 0][lr] = bv.x; Bs[lq * 4 + 1][lr] = bv.y;
        Bs[lq * 4 + 2][lr] = bv.z; Bs[lq * 4 + 3][lr] = bv.w;
        __syncthreads();
#pragma unroll
        for (int k = 0; k < 16; k++) {
            float4 a = *(const float4*)&As[k][tm * 4];
            float4 q = *(const float4*)&Bs[k][tn * 4];
            acc[0][0] += a.x * q.x; acc[0][1] += a.x * q.y; acc[0][2] += a.x * q.z; acc[0][3] += a.x * q.w;
            acc[1][0] += a.y * q.x; acc[1][1] += a.y * q.y; acc[1][2] += a.y * q.z; acc[1][3] += a.y * q.w;
            acc[2][0] += a.z * q.x; acc[2][1] += a.z * q.y; acc[2][2] += a.z * q.z; acc[2][3] += a.z * q.w;
            acc[3][0] += a.w * q.x; acc[3][1] += a.w * q.y; acc[3][2] += a.w * q.z; acc[3][3] += a.w * q.w;
        }
    }
    int nb = n0 + tm * 4, mb = m0 + tn * 4;
    float im[4];
#pragma unroll
    for (int j = 0; j < 4; j++) im[j] = ivt[b * 128 + mb + j];
#pragma unroll
    for (int i = 0; i < 4; i++) {
        float in_ = ivv[b * 128 + nb + i];
        float4 o;
        o.x = 1.0f - acc[i][0] * in_ * im[0];
        o.y = 1.0f - acc[i][1] * in_ * im[1];
        o.z = 1.0f - acc[i][2] * in_ * im[2];
        o.w = 1.0f - acc[i][3] * in_ * im[3];
        *(float4*)&cost[((size_t)b * 128 + nb + i) * 128 + mb] = o;
    }
}

// ================= Hungarian: LAPJV (colred + 2x ARR + augmentation) ============
// One wave per batch problem, 128 blocks. Lane owns columns {lane, lane+64} and
// rows {lane, lane+64}. Cost packed fp16 half2 in LDS (one b32 read per row).
#define HUNG_INF 3.0e38f

__device__ __forceinline__ int rdlane_i(int v, int l) {
    return __builtin_amdgcn_readlane(v, l);
}
__device__ __forceinline__ float rdlane_f(float v, int l) {
    return __int_as_float(__builtin_amdgcn_readlane(__float_as_int(v), l));
}

// full-wave u32 min via DPP (identity UINT_MAX); result valid in lane 63
__device__ __forceinline__ unsigned int dpp_umin_wave(unsigned int x) {
    int o;
    o = __builtin_amdgcn_update_dpp(-1, (int)x, 0x111, 0xF, 0xF, false); // row_shr:1
    x = (x < (unsigned int)o) ? x : (unsigned int)o;
    o = __builtin_amdgcn_update_dpp(-1, (int)x, 0x112, 0xF, 0xF, false); // row_shr:2
    x = (x < (unsigned int)o) ? x : (unsigned int)o;
    o = __builtin_amdgcn_update_dpp(-1, (int)x, 0x114, 0xF, 0xF, false); // row_shr:4
    x = (x < (unsigned int)o) ? x : (unsigned int)o;
    o = __builtin_amdgcn_update_dpp(-1, (int)x, 0x118, 0xF, 0xF, false); // row_shr:8
    x = (x < (unsigned int)o) ? x : (unsigned int)o;
    o = __builtin_amdgcn_update_dpp(-1, (int)x, 0x142, 0xF, 0xF, false); // row_bcast:15
    x = (x < (unsigned int)o) ? x : (unsigned int)o;
    o = __builtin_amdgcn_update_dpp(-1, (int)x, 0x143, 0xF, 0xF, false); // row_bcast:31
    x = (x < (unsigned int)o) ? x : (unsigned int)o;
    return x;
}

__device__ __forceinline__ unsigned int pack_h2(float a, float b) {
    unsigned int ua = (unsigned int)__half_as_ushort(__float2half(a));
    unsigned int ub = (unsigned int)__half_as_ushort(__float2half(b));
    return ua | (ub << 16);
}
__device__ __forceinline__ float h2_lo(unsigned int u) {
    return __half2float(__ushort_as_half((unsigned short)(u & 0xFFFFu)));
}
__device__ __forceinline__ float h2_hi(unsigned int u) {
    return __half2float(__ushort_as_half((unsigned short)(u >> 16)));
}
// sortable key: biased value bits (top 25) | column index (low 7). val >= -eps.
__device__ __forceinline__ unsigned int vkey(float v, int idx) {
    return (__float_as_uint(v + 1.0f) & 0xFFFFFF80u) | (unsigned int)idx;
}

__global__ __launch_bounds__(64) void k_hungarian(const float* __restrict__ cost,
                                                  int* __restrict__ cols) {
    __shared__ unsigned int P[128 * 64];   // 32 KB packed fp16 cost
    __shared__ int freelist[136];
    int b = blockIdx.x;
    int lane = threadIdx.x;
    const float* C = cost + (size_t)b * 16384;
#pragma unroll 4
    for (int r = 0; r < 128; ++r)
        P[r * 64 + lane] = pack_h2(C[r * 128 + lane], C[r * 128 + 64 + lane]);
    __syncthreads();

    // ---- phase 1: column reduction (v[j] = min_i c[i][j], argmin keeps lowest i) ----
    float vA = HUNG_INF, vB = HUNG_INF;   // col duals: v[lane], v[lane+64]
    int yA = 0, yB = 0;                   // argmin rows
    for (int r = 0; r < 128; ++r) {
        unsigned int pk = P[r * 64 + lane];
        float a = h2_lo(pk), bb = h2_hi(pk);
        if (a < vA) { vA = a; yA = r; }
        if (bb < vB) { vB = bb; yB = r; }
    }
    int p0 = -1, p1 = -1;     // row matched to col lane / lane+64
    int x0 = -1, x1 = -1;     // col matched to row lane / lane+64 (preprocessing only)
    float u0 = 0.0f, u1 = 0.0f;   // row duals
    for (int j = 127; j >= 0; --j) {   // descending, like _ccrrt_dense
        int yi = rdlane_i(j >= 64 ? yB : yA, j & 63);
        int xi = rdlane_i(yi >= 64 ? x1 : x0, yi & 63);
        if (xi < 0) {
            if (lane == (yi & 63)) { if (yi < 64) x0 = j; else x1 = j; }
            if (lane == (j & 63)) { if (j < 64) p0 = yi; else p1 = yi; }
        }
    }
    // ---- build free-row list (ascending row order) ----
    unsigned long long fm0 = __ballot(x0 < 0);
    unsigned long long fm1 = __ballot(x1 < 0);
    int half0 = __popcll(fm0);
    int nfree = half0 + __popcll(fm1);
    if (x0 < 0) freelist[__popcll(fm0 & ((1ull << lane) - 1))] = lane;
    if (x1 < 0) freelist[half0 + __popcll(fm1 & ((1ull << lane) - 1))] = lane + 64;
    __syncthreads();

    // ---- phase 2: augmenting row reduction x2 (lap _carr_dense semantics) ----
    for (int pass = 0; pass < 2 && nfree > 0; ++pass) {
        int cur = 0, nnew = 0, rr = 0;
        while (cur < nfree) {
            int fi = freelist[cur]; cur++;
            rr++;
            if (rr >= 600 || rr >= cur * 128) {
                // safety drain: give up on fi; phase 3 (exact) will handle it
                if (lane == 0) freelist[nnew] = fi;
                nnew++;
                continue;
            }
            unsigned int pk = P[fi * 64 + lane];
            float rc0 = h2_lo(pk) - vA;
            float rc1 = h2_hi(pk) - vB;
            unsigned int k0 = vkey(rc0, lane);
            unsigned int k1 = vkey(rc1, lane + 64);
            unsigned int km = dpp_umin_wave(k0 < k1 ? k0 : k1);
            int j1 = (int)((unsigned int)rdlane_i((int)km, 63) & 127u);
            float vmin = rdlane_f(j1 >= 64 ? rc1 : rc0, j1 & 63);   // exact
            unsigned int k0m = (j1 == lane) ? 0xFFFFFFFFu : k0;      // mask min ELEMENT
            unsigned int k1m = (j1 == lane + 64) ? 0xFFFFFFFFu : k1;
            unsigned int km2 = dpp_umin_wave(k0m < k1m ? k0m : k1m);
            int j2 = (int)((unsigned int)rdlane_i((int)km2, 63) & 127u);
            float vsec = rdlane_f(j2 >= 64 ? rc1 : rc0, j2 & 63);   // exact
            int i0 = rdlane_i(j1 >= 64 ? p1 : p0, j1 & 63);
            bool lowers = vmin < vsec;
            if (lowers) {
                if (lane == (j1 & 63)) {
                    if (j1 < 64) vA -= (vsec - vmin); else vB -= (vsec - vmin);
                }
            } else if (i0 >= 0) {        // tie: switch to second-min column
                j1 = j2;
                i0 = rdlane_i(j1 >= 64 ? p1 : p0, j1 & 63);
            }
            if (i0 >= 0) {
                if (lowers) { cur--; if (lane == 0) freelist[cur] = i0; }  // reprocess now
                else { if (lane == 0) freelist[nnew] = i0; nnew++; }       // next pass
            }
            // assign fi -> j1; u[fi] = vsec keeps the matched edge tight & duals feasible
            if (lane == (j1 & 63)) { if (j1 < 64) p0 = fi; else p1 = fi; }
            if (lane == (fi & 63)) { if (fi < 64) u0 = vsec; else u1 = vsec; }
        }
        nfree = nnew;
    }

    // ---- phase 3: exact Dijkstra augmentation for remaining free rows ----
    for (int fx = 0; fx < nfree; ++fx) {
        int row = freelist[fx];
        float minv0 = HUNG_INF, minv1 = HUNG_INF;
        int way0 = 128, way1 = 128;
        bool used0 = false, used1 = false;
        bool intree0 = (row < 64) && (lane == row);
        bool intree1 = (row >= 64) && (lane == row - 64);
        int j0 = 128;        // virtual root column
        int i0r = row;       // row to expand
        while (true) {
            float ui = rdlane_f(i0r >= 64 ? u1 : u0, i0r & 63);
            unsigned int pk = P[i0r * 64 + lane];
            float cur0 = h2_lo(pk) - ui - vA;
            float cur1 = h2_hi(pk) - ui - vB;
            if (!used0 && cur0 < minv0) { minv0 = cur0; way0 = j0; }
            if (!used1 && cur1 < minv1) { minv1 = cur1; way1 = j0; }
            float cand0 = used0 ? HUNG_INF : minv0;
            float cand1 = used1 ? HUNG_INF : minv1;
            unsigned int k0 = vkey(cand0, lane);
            unsigned int k1 = vkey(cand1, lane + 64);
            unsigned int km = dpp_umin_wave(k0 < k1 ? k0 : k1);
            unsigned int kmin = (unsigned int)rdlane_i((int)km, 63);
            int j1 = (int)(kmin & 127u);
            float delta = __uint_as_float(kmin & 0xFFFFFF80u) - 1.0f;  // <= exact min
            if (used0) vA -= delta; else minv0 -= delta;
            if (used1) vB -= delta; else minv1 -= delta;
            if (intree0) u0 += delta;
            if (intree1) u1 += delta;
            int pj = rdlane_i(j1 >= 64 ? p1 : p0, j1 & 63);
            if (pj >= 0) {
                if (lane == (j1 & 63)) { if (j1 >= 64) used1 = true; else used0 = true; }
                if (lane == (pj & 63)) { if (pj < 64) intree0 = true; else intree1 = true; }
                j0 = j1;
                i0r = pj;
            } else {
                // augment along alternating path from j1
                int j = j1;
                while (j != 128) {
                    int w = rdlane_i(j >= 64 ? way1 : way0, j & 63);
                    int pw = (w == 128) ? row : rdlane_i(w >= 64 ? p1 : p0, w & 63);
                    if (lane == (j & 63)) { if (j >= 64) p1 = pw; else p0 = pw; }
                    j = w;
                }
                break;
            }
        }
    }
    // p[j] = row matched to column j  ->  cols[row] = j
    cols[b * 128 + p0] = lane;
    cols[b * 128 + p1] = lane + 64;
}

// ---------------- node MSE: one block per (b,n) row ----------------
__global__ __launch_bounds__(256) void k_node(const float* __restrict__ V,
                                              const float* __restrict__ T,
                                              const int* __restrict__ cols,
                                              float* __restrict__ acc) {
    int bn = blockIdx.x;
    int b = bn >> 7, n = bn & 127;
    int c = cols[bn];
    const float* vr = V + ((size_t)b * 128 + n) * 1024;
    const float* tr = T + ((size_t)b * 128 + c) * 1024;
    int t = threadIdx.x;
    float4 a = *(const float4*)&vr[t * 4];
    float4 bb = *(const float4*)&tr[t * 4];
    float dx = a.x - bb.x, dy = a.y - bb.y, dz = a.z - bb.z, dw = a.w - bb.w;
    float s = dx * dx + dy * dy + dz * dz + dw * dw;
#pragma unroll
    for (int off = 32; off > 0; off >>= 1) s += __shfl_xor(s, off);
    __shared__ float wsum[4];
    if ((t & 63) == 0) wsum[t >> 6] = s;
    __syncthreads();
    if (t == 0) atomicAdd(&acc[1], wsum[0] + wsum[1] + wsum[2] + wsum[3]);
}

// ---------------- graph MSE ----------------
__global__ __launch_bounds__(256) void k_graph(const float* __restrict__ Av,
                                               const float* __restrict__ At,
                                               float* __restrict__ acc) {
    size_t idx = ((size_t)blockIdx.x * 256 + threadIdx.x) * 4;
    float4 a = *(const float4*)&Av[idx];
    float4 bb = *(const float4*)&At[idx];
    float dx = a.x - bb.x, dy = a.y - bb.y, dz = a.z - bb.z, dw = a.w - bb.w;
    float s = dx * dx + dy * dy + dz * dz + dw * dw;
#pragma unroll
    for (int off = 32; off > 0; off >>= 1) s += __shfl_xor(s, off);
    __shared__ float wsum[4];
    int t = threadIdx.x;
    if ((t & 63) == 0) wsum[t >> 6] = s;
    __syncthreads();
    if (t == 0) atomicAdd(&acc[2], wsum[0] + wsum[1] + wsum[2] + wsum[3]);
}

// ---------------- finalize ----------------
__global__ void k_final(const float* __restrict__ acc, float* __restrict__ out) {
    float lg = acc[0];
    float ln = acc[1] / 16777216.0f;   // 128*128*1024
    float lgr = acc[2] / 2097152.0f;   // 128*128*128
    out[0] = lg + ln + lgr;
    out[1] = lg;
    out[2] = ln;
    out[3] = lgr;
}

extern "C" void kernel_launch(void* const* d_in, const int* in_sizes, int n_in,
                              void* d_out, int out_size, void* d_ws, size_t ws_size,
                              hipStream_t stream) {
    const float* vg = (const float*)d_in[0];
    const float* tg = (const float*)d_in[1];
    const float* V  = (const float*)d_in[2];
    const float* T  = (const float*)d_in[3];
    const float* Av = (const float*)d_in[4];
    const float* At = (const float*)d_in[5];
    float* out = (float*)d_out;
    float* ws = (float*)d_ws;

    float* cost = ws + WS_COST;
    float* sim  = ws + WS_SIM;
    float* ivg  = ws + WS_IVG;
    float* itg  = ws + WS_ITG;
    float* ivv  = ws + WS_IVV;
    float* ivt  = ws + WS_IVT;
    int*   cols = (int*)(ws + WS_COLS);
    float* acc  = ws + WS_ACC;

    k_init<<<1, 16, 0, stream>>>(acc);

    k_invnorm<<<32, 256, 0, stream>>>(vg, ivg, 128);
    k_invnorm<<<32, 256, 0, stream>>>(tg, itg, 128);
    k_invnorm<<<4096, 256, 0, stream>>>(V, ivv, 16384);
    k_invnorm<<<4096, 256, 0, stream>>>(T, ivt, 16384);

    k_sim<<<128, 128, 0, stream>>>(vg, tg, ivg, itg, sim);
    k_global<<<1, 128, 0, stream>>>(sim, acc);

    k_cost<<<512, 256, 0, stream>>>(V, T, ivv, ivt, cost);
    k_hungarian<<<128, 64, 0, stream>>>(cost, cols);

    k_node<<<16384, 256, 0, stream>>>(V, T, cols, acc);
    k_graph<<<2048, 256, 0, stream>>>(Av, At, acc);

    k_final<<<1, 1, 0, stream>>>(acc, out);
}

// Round 6
// 698.939 us; speedup vs baseline: 1.7939x; 1.0021x over previous
//
#include <hip/hip_runtime.h>
#include <hip/hip_fp16.h>
#include <math.h>

#define TEMPERATURE 0.07f

// ---------------- ws layout (float offsets) ----------------
#define WS_COST   0          // 128*128*128 = 2097152
#define WS_SIM    2097152    // 16384
#define WS_IVG    2113536    // 128
#define WS_ITG    2113664    // 128
#define WS_IVV    2113792    // 16384
#define WS_IVT    2130176    // 16384
#define WS_COLS   2146560    // 16384 ints
#define WS_ACC    2162944    // 16 floats

// ---------------- init: zero accumulators ----------------
__global__ void k_init(float* acc) {
    if (threadIdx.x < 16) acc[threadIdx.x] = 0.0f;
}

// ---------------- row inverse norms: x [rows][1024] ----------------
__global__ __launch_bounds__(256) void k_invnorm(const float* __restrict__ x,
                                                 float* __restrict__ out, int rows) {
    int wid = threadIdx.x >> 6;
    int lane = threadIdx.x & 63;
    int row = blockIdx.x * 4 + wid;
    if (row >= rows) return;
    const float* xr = x + (size_t)row * 1024;
    float s = 0.0f;
#pragma unroll
    for (int i = 0; i < 4; i++) {
        float4 v = *(const float4*)&xr[i * 256 + lane * 4];
        s += v.x * v.x + v.y * v.y + v.z * v.z + v.w * v.w;
    }
#pragma unroll
    for (int off = 32; off > 0; off >>= 1) s += __shfl_xor(s, off);
    if (lane == 0) out[row] = 1.0f / fmaxf(sqrtf(s), 1e-12f);
}

// ---------------- sim[i][j] = dot(v_g[i], t_g[j]) * iv[i]*it[j] / TEMP ----------------
__global__ __launch_bounds__(128) void k_sim(const float* __restrict__ vg,
                                             const float* __restrict__ tg,
                                             const float* __restrict__ ivg,
                                             const float* __restrict__ itg,
                                             float* __restrict__ sim) {
    int i = blockIdx.x, j = threadIdx.x;
    const float* vr = vg + (size_t)i * 1024;
    const float* tr = tg + (size_t)j * 1024;
    float acc = 0.0f;
    for (int k = 0; k < 1024; k += 4) {
        float4 a = *(const float4*)&vr[k];
        float4 b = *(const float4*)&tr[k];
        acc += a.x * b.x + a.y * b.y + a.z * b.z + a.w * b.w;
    }
    sim[i * 128 + j] = acc * ivg[i] * itg[j] / TEMPERATURE;
}

// ---------------- L_global from sim (single block, 128 threads) ----------------
__global__ __launch_bounds__(128) void k_global(const float* __restrict__ sim,
                                                float* __restrict__ acc) {
    __shared__ float S[128 * 128];   // 64 KB: stage sim once, coalesced
    __shared__ float red[128];
    int t = threadIdx.x;
    for (int i = t * 4; i < 16384; i += 512)
        *(float4*)&S[i] = *(const float4*)&sim[i];
    __syncthreads();
    float m = -3e38f, m2 = -3e38f;
    for (int j = 0; j < 128; j++) {
        m = fmaxf(m, S[t * 128 + j]);
        m2 = fmaxf(m2, S[j * 128 + t]);
    }
    float s = 0.0f, s2 = 0.0f;
    for (int j = 0; j < 128; j++) {
        s += expf(S[t * 128 + j] - m);
        s2 += expf(S[j * 128 + t] - m2);
    }
    float contrib = 2.0f * S[t * 128 + t] - (m + logf(s)) - (m2 + logf(s2));
    red[t] = contrib;
    __syncthreads();
    for (int o = 64; o > 0; o >>= 1) {
        if (t < o) red[t] += red[t + o];
        __syncthreads();
    }
    if (t == 0) acc[0] = -red[0] / 256.0f;   // 0.5*(mean+mean), negated
}

// ---------------- cost[b][n][m] = 1 - cos(V[b,n], T[b,m])  (bf16 MFMA) --------
// Block = (batch, row-half): 64x128 outputs. 4 waves in 2x2; wave tile 32x64 =
// 2x4 frags of 16x16, K-loop in steps of 32. On-the-fly f32 -> normalized bf16
// conversion; no LDS, no barriers; fragments load 16 full cache lines/inst.
typedef __attribute__((ext_vector_type(8))) short short8v;
typedef __attribute__((ext_vector_type(4))) float f32x4;

__device__ __forceinline__ short bf16rne(float f) {
    unsigned int u = __float_as_uint(f);
    u += 0x7FFFu + ((u >> 16) & 1u);
    return (short)(u >> 16);
}
__device__ __forceinline__ short8v cvt8(const float* __restrict__ p, float s) {
    float4 x = *(const float4*)p;
    float4 y = *(const float4*)(p + 4);
    short8v r;
    r[0] = bf16rne(x.x * s); r[1] = bf16rne(x.y * s);
    r[2] = bf16rne(x.z * s); r[3] = bf16rne(x.w * s);
    r[4] = bf16rne(y.x * s); r[5] = bf16rne(y.y * s);
    r[6] = bf16rne(y.z * s); r[7] = bf16rne(y.w * s);
    return r;
}

__global__ __launch_bounds__(256) void k_cost(const float* __restrict__ V,
                                              const float* __restrict__ T,
                                              const float* __restrict__ ivv,
                                              const float* __restrict__ ivt,
                                              float* __restrict__ cost) {
    int b = blockIdx.x >> 1;
    int half = blockIdx.x & 1;
    int w = threadIdx.x >> 6;
    int lane = threadIdx.x & 63;
    int n0 = half * 64 + (w >> 1) * 32;   // wave's 32-row base
    int m0 = (w & 1) * 64;                // wave's 64-col base
    int ar = lane & 15, kq = lane >> 4;
    const float* Vb = V + (size_t)b * 131072;
    const float* Tb = T + (size_t)b * 131072;
    float sA0 = ivv[b * 128 + n0 + ar];
    float sA1 = ivv[b * 128 + n0 + 16 + ar];
    float sB0 = ivt[b * 128 + m0 + ar];
    float sB1 = ivt[b * 128 + m0 + 16 + ar];
    float sB2 = ivt[b * 128 + m0 + 32 + ar];
    float sB3 = ivt[b * 128 + m0 + 48 + ar];
    f32x4 zero = {0.0f, 0.0f, 0.0f, 0.0f};
    f32x4 acc[2][4];
#pragma unroll
    for (int i = 0; i < 2; i++)
#pragma unroll
        for (int j = 0; j < 4; j++) acc[i][j] = zero;

    for (int k0 = 0; k0 < 1024; k0 += 32) {
        int ko = k0 + kq * 8;
        short8v a0 = cvt8(&Vb[(size_t)(n0 + ar) * 1024 + ko], sA0);
        short8v a1 = cvt8(&Vb[(size_t)(n0 + 16 + ar) * 1024 + ko], sA1);
        short8v b0 = cvt8(&Tb[(size_t)(m0 + ar) * 1024 + ko], sB0);
        short8v b1 = cvt8(&Tb[(size_t)(m0 + 16 + ar) * 1024 + ko], sB1);
        short8v b2 = cvt8(&Tb[(size_t)(m0 + 32 + ar) * 1024 + ko], sB2);
        short8v b3 = cvt8(&Tb[(size_t)(m0 + 48 + ar) * 1024 + ko], sB3);
        acc[0][0] = __builtin_amdgcn_mfma_f32_16x16x32_bf16(a0, b0, acc[0][0], 0, 0, 0);
        acc[0][1] = __builtin_amdgcn_mfma_f32_16x16x32_bf16(a0, b1, acc[0][1], 0, 0, 0);
        acc[0][2] = __builtin_amdgcn_mfma_f32_16x16x32_bf16(a0, b2, acc[0][2], 0, 0, 0);
        acc[0][3] = __builtin_amdgcn_mfma_f32_16x16x32_bf16(a0, b3, acc[0][3], 0, 0, 0);
        acc[1][0] = __builtin_amdgcn_mfma_f32_16x16x32_bf16(a1, b0, acc[1][0], 0, 0, 0);
        acc[1][1] = __builtin_amdgcn_mfma_f32_16x16x32_bf16(a1, b1, acc[1][1], 0, 0, 0);
        acc[1][2] = __builtin_amdgcn_mfma_f32_16x16x32_bf16(a1, b2, acc[1][2], 0, 0, 0);
        acc[1][3] = __builtin_amdgcn_mfma_f32_16x16x32_bf16(a1, b3, acc[1][3], 0, 0, 0);
    }
    // D layout: row = (lane>>4)*4 + r, col = lane&15  [m89 verified]
#pragma unroll
    for (int i = 0; i < 2; i++)
#pragma unroll
        for (int j = 0; j < 4; j++)
#pragma unroll
            for (int r = 0; r < 4; r++) {
                int rowi = n0 + i * 16 + kq * 4 + r;
                int colj = m0 + j * 16 + ar;
                cost[((size_t)b * 128 + rowi) * 128 + colj] = 1.0f - acc[i][j][r];
            }
}

// ================= Hungarian: LAPJV (colred + 2x ARR + augmentation) ============
// One wave per batch problem, 128 blocks. Lane owns columns {lane, lane+64} and
// rows {lane, lane+64}. Cost packed fp16 half2 in LDS (one b32 read per row).
#define HUNG_INF 3.0e38f

__device__ __forceinline__ int rdlane_i(int v, int l) {
    return __builtin_amdgcn_readlane(v, l);
}
__device__ __forceinline__ float rdlane_f(float v, int l) {
    return __int_as_float(__builtin_amdgcn_readlane(__float_as_int(v), l));
}

// full-wave u32 min via DPP (identity UINT_MAX); result valid in lane 63
__device__ __forceinline__ unsigned int dpp_umin_wave(unsigned int x) {
    int o;
    o = __builtin_amdgcn_update_dpp(-1, (int)x, 0x111, 0xF, 0xF, false); // row_shr:1
    x = (x < (unsigned int)o) ? x : (unsigned int)o;
    o = __builtin_amdgcn_update_dpp(-1, (int)x, 0x112, 0xF, 0xF, false); // row_shr:2
    x = (x < (unsigned int)o) ? x : (unsigned int)o;
    o = __builtin_amdgcn_update_dpp(-1, (int)x, 0x114, 0xF, 0xF, false); // row_shr:4
    x = (x < (unsigned int)o) ? x : (unsigned int)o;
    o = __builtin_amdgcn_update_dpp(-1, (int)x, 0x118, 0xF, 0xF, false); // row_shr:8
    x = (x < (unsigned int)o) ? x : (unsigned int)o;
    o = __builtin_amdgcn_update_dpp(-1, (int)x, 0x142, 0xF, 0xF, false); // row_bcast:15
    x = (x < (unsigned int)o) ? x : (unsigned int)o;
    o = __builtin_amdgcn_update_dpp(-1, (int)x, 0x143, 0xF, 0xF, false); // row_bcast:31
    x = (x < (unsigned int)o) ? x : (unsigned int)o;
    return x;
}

__device__ __forceinline__ unsigned int pack_h2(float a, float b) {
    unsigned int ua = (unsigned int)__half_as_ushort(__float2half(a));
    unsigned int ub = (unsigned int)__half_as_ushort(__float2half(b));
    return ua | (ub << 16);
}
__device__ __forceinline__ float h2_lo(unsigned int u) {
    return __half2float(__ushort_as_half((unsigned short)(u & 0xFFFFu)));
}
__device__ __forceinline__ float h2_hi(unsigned int u) {
    return __half2float(__ushort_as_half((unsigned short)(u >> 16)));
}
// sortable key: biased value bits (top 25) | column index (low 7). val >= -eps.
__device__ __forceinline__ unsigned int vkey(float v, int idx) {
    return (__float_as_uint(v + 1.0f) & 0xFFFFFF80u) | (unsigned int)idx;
}

__global__ __launch_bounds__(64) void k_hungarian(const float* __restrict__ cost,
                                                  int* __restrict__ cols) {
    __shared__ unsigned int P[128 * 64];   // 32 KB packed fp16 cost
    __shared__ int freelist[136];
    int b = blockIdx.x;
    int lane = threadIdx.x;
    const float* C = cost + (size_t)b * 16384;
#pragma unroll 4
    for (int r = 0; r < 128; ++r)
        P[r * 64 + lane] = pack_h2(C[r * 128 + lane], C[r * 128 + 64 + lane]);
    __syncthreads();

    // ---- phase 1: column reduction (v[j] = min_i c[i][j], argmin keeps lowest i) ----
    float vA = HUNG_INF, vB = HUNG_INF;   // col duals: v[lane], v[lane+64]
    int yA = 0, yB = 0;                   // argmin rows
    for (int r = 0; r < 128; ++r) {
        unsigned int pk = P[r * 64 + lane];
        float a = h2_lo(pk), bb = h2_hi(pk);
        if (a < vA) { vA = a; yA = r; }
        if (bb < vB) { vB = bb; yB = r; }
    }
    int p0 = -1, p1 = -1;     // row matched to col lane / lane+64
    int x0 = -1, x1 = -1;     // col matched to row lane / lane+64 (preprocessing only)
    float u0 = 0.0f, u1 = 0.0f;   // row duals
    for (int j = 127; j >= 0; --j) {   // descending, like _ccrrt_dense
        int yi = rdlane_i(j >= 64 ? yB : yA, j & 63);
        int xi = rdlane_i(yi >= 64 ? x1 : x0, yi & 63);
        if (xi < 0) {
            if (lane == (yi & 63)) { if (yi < 64) x0 = j; else x1 = j; }
            if (lane == (j & 63)) { if (j < 64) p0 = yi; else p1 = yi; }
        }
    }
    // ---- build free-row list (ascending row order) ----
    unsigned long long fm0 = __ballot(x0 < 0);
    unsigned long long fm1 = __ballot(x1 < 0);
    int half0 = __popcll(fm0);
    int nfree = half0 + __popcll(fm1);
    if (x0 < 0) freelist[__popcll(fm0 & ((1ull << lane) - 1))] = lane;
    if (x1 < 0) freelist[half0 + __popcll(fm1 & ((1ull << lane) - 1))] = lane + 64;
    __syncthreads();

    // ---- phase 2: augmenting row reduction x2 (lap _carr_dense semantics) ----
    for (int pass = 0; pass < 2 && nfree > 0; ++pass) {
        int cur = 0, nnew = 0, rr = 0;
        while (cur < nfree) {
            int fi = freelist[cur]; cur++;
            rr++;
            if (rr >= 600 || rr >= cur * 128) {
                // safety drain: give up on fi; phase 3 (exact) will handle it
                if (lane == 0) freelist[nnew] = fi;
                nnew++;
                continue;
            }
            unsigned int pk = P[fi * 64 + lane];
            float rc0 = h2_lo(pk) - vA;
            float rc1 = h2_hi(pk) - vB;
            unsigned int k0 = vkey(rc0, lane);
            unsigned int k1 = vkey(rc1, lane + 64);
            unsigned int km = dpp_umin_wave(k0 < k1 ? k0 : k1);
            int j1 = (int)((unsigned int)rdlane_i((int)km, 63) & 127u);
            float vmin = rdlane_f(j1 >= 64 ? rc1 : rc0, j1 & 63);   // exact
            unsigned int k0m = (j1 == lane) ? 0xFFFFFFFFu : k0;      // mask min ELEMENT
            unsigned int k1m = (j1 == lane + 64) ? 0xFFFFFFFFu : k1;
            unsigned int km2 = dpp_umin_wave(k0m < k1m ? k0m : k1m);
            int j2 = (int)((unsigned int)rdlane_i((int)km2, 63) & 127u);
            float vsec = rdlane_f(j2 >= 64 ? rc1 : rc0, j2 & 63);   // exact
            int i0 = rdlane_i(j1 >= 64 ? p1 : p0, j1 & 63);
            bool lowers = vmin < vsec;
            if (lowers) {
                if (lane == (j1 & 63)) {
                    if (j1 < 64) vA -= (vsec - vmin); else vB -= (vsec - vmin);
                }
            } else if (i0 >= 0) {        // tie: switch to second-min column
                j1 = j2;
                i0 = rdlane_i(j1 >= 64 ? p1 : p0, j1 & 63);
            }
            if (i0 >= 0) {
                if (lowers) { cur--; if (lane == 0) freelist[cur] = i0; }  // reprocess now
                else { if (lane == 0) freelist[nnew] = i0; nnew++; }       // next pass
            }
            // assign fi -> j1; u[fi] = vsec keeps the matched edge tight & duals feasible
            if (lane == (j1 & 63)) { if (j1 < 64) p0 = fi; else p1 = fi; }
            if (lane == (fi & 63)) { if (fi < 64) u0 = vsec; else u1 = vsec; }
        }
        nfree = nnew;
    }

    // ---- phase 3: exact Dijkstra augmentation for remaining free rows ----
    // Software-pipelined: next expansion row's LDS word + u[pj] are fetched as
    // soon as pj is resolved (pj not yet in tree -> its dual is unaffected by
    // this step's delta), hiding LDS latency under the dual-update tail.
    for (int fx = 0; fx < nfree; ++fx) {
        int row = freelist[fx];
        float minv0 = HUNG_INF, minv1 = HUNG_INF;
        int way0 = 128, way1 = 128;
        bool used0 = false, used1 = false;
        bool intree0 = (row < 64) && (lane == row);
        bool intree1 = (row >= 64) && (lane == row - 64);
        int j0 = 128;        // virtual root column
        float ui = rdlane_f(row >= 64 ? u1 : u0, row & 63);
        unsigned int pk = P[row * 64 + lane];
        while (true) {
            float cur0 = h2_lo(pk) - ui - vA;
            float cur1 = h2_hi(pk) - ui - vB;
            if (!used0 && cur0 < minv0) { minv0 = cur0; way0 = j0; }
            if (!used1 && cur1 < minv1) { minv1 = cur1; way1 = j0; }
            float cand0 = used0 ? HUNG_INF : minv0;
            float cand1 = used1 ? HUNG_INF : minv1;
            unsigned int k0 = vkey(cand0, lane);
            unsigned int k1 = vkey(cand1, lane + 64);
            unsigned int km = dpp_umin_wave(k0 < k1 ? k0 : k1);
            unsigned int kmin = (unsigned int)rdlane_i((int)km, 63);
            int j1 = (int)(kmin & 127u);
            float delta = __uint_as_float(kmin & 0xFFFFFF80u) - 1.0f;  // <= exact min
            int pj = rdlane_i(j1 >= 64 ? p1 : p0, j1 & 63);
            int nr = (pj >= 0) ? pj : 0;
            unsigned int pk2 = P[nr * 64 + lane];                      // prefetch row
            float ui2 = rdlane_f(nr >= 64 ? u1 : u0, nr & 63);         // prefetch dual
            if (used0) vA -= delta; else minv0 -= delta;
            if (used1) vB -= delta; else minv1 -= delta;
            if (intree0) u0 += delta;
            if (intree1) u1 += delta;
            if (pj >= 0) {
                if (lane == (j1 & 63)) { if (j1 >= 64) used1 = true; else used0 = true; }
                if (lane == (pj & 63)) { if (pj < 64) intree0 = true; else intree1 = true; }
                j0 = j1;
                pk = pk2;
                ui = ui2;
            } else {
                // augment along alternating path from j1
                int j = j1;
                while (j != 128) {
                    int w = rdlane_i(j >= 64 ? way1 : way0, j & 63);
                    int pw = (w == 128) ? row : rdlane_i(w >= 64 ? p1 : p0, w & 63);
                    if (lane == (j & 63)) { if (j >= 64) p1 = pw; else p0 = pw; }
                    j = w;
                }
                break;
            }
        }
    }
    // p[j] = row matched to column j  ->  cols[row] = j
    cols[b * 128 + p0] = lane;
    cols[b * 128 + p1] = lane + 64;
}

// ---------------- node MSE: one block per (b,n) row ----------------
__global__ __launch_bounds__(256) void k_node(const float* __restrict__ V,
                                              const float* __restrict__ T,
                                              const int* __restrict__ cols,
                                              float* __restrict__ acc) {
    int bn = blockIdx.x;
    int b = bn >> 7, n = bn & 127;
    int c = cols[bn];
    const float* vr = V + ((size_t)b * 128 + n) * 1024;
    const float* tr = T + ((size_t)b * 128 + c) * 1024;
    int t = threadIdx.x;
    float4 a = *(const float4*)&vr[t * 4];
    float4 bb = *(const float4*)&tr[t * 4];
    float dx = a.x - bb.x, dy = a.y - bb.y, dz = a.z - bb.z, dw = a.w - bb.w;
    float s = dx * dx + dy * dy + dz * dz + dw * dw;
#pragma unroll
    for (int off = 32; off > 0; off >>= 1) s += __shfl_xor(s, off);
    __shared__ float wsum[4];
    if ((t & 63) == 0) wsum[t >> 6] = s;
    __syncthreads();
    if (t == 0) atomicAdd(&acc[1], wsum[0] + wsum[1] + wsum[2] + wsum[3]);
}

// ---------------- graph MSE ----------------
__global__ __launch_bounds__(256) void k_graph(const float* __restrict__ Av,
                                               const float* __restrict__ At,
                                               float* __restrict__ acc) {
    size_t idx = ((size_t)blockIdx.x * 256 + threadIdx.x) * 4;
    float4 a = *(const float4*)&Av[idx];
    float4 bb = *(const float4*)&At[idx];
    float dx = a.x - bb.x, dy = a.y - bb.y, dz = a.z - bb.z, dw = a.w - bb.w;
    float s = dx * dx + dy * dy + dz * dz + dw * dw;
#pragma unroll
    for (int off = 32; off > 0; off >>= 1) s += __shfl_xor(s, off);
    __shared__ float wsum[4];
    int t = threadIdx.x;
    if ((t & 63) == 0) wsum[t >> 6] = s;
    __syncthreads();
    if (t == 0) atomicAdd(&acc[2], wsum[0] + wsum[1] + wsum[2] + wsum[3]);
}

// ---------------- finalize ----------------
__global__ void k_final(const float* __restrict__ acc, float* __restrict__ out) {
    float lg = acc[0];
    float ln = acc[1] / 16777216.0f;   // 128*128*1024
    float lgr = acc[2] / 2097152.0f;   // 128*128*128
    out[0] = lg + ln + lgr;
    out[1] = lg;
    out[2] = ln;
    out[3] = lgr;
}

extern "C" void kernel_launch(void* const* d_in, const int* in_sizes, int n_in,
                              void* d_out, int out_size, void* d_ws, size_t ws_size,
                              hipStream_t stream) {
    const float* vg = (const float*)d_in[0];
    const float* tg = (const float*)d_in[1];
    const float* V  = (const float*)d_in[2];
    const float* T  = (const float*)d_in[3];
    const float* Av = (const float*)d_in[4];
    const float* At = (const float*)d_in[5];
    float* out = (float*)d_out;
    float* ws = (float*)d_ws;

    float* cost = ws + WS_COST;
    float* sim  = ws + WS_SIM;
    float* ivg  = ws + WS_IVG;
    float* itg  = ws + WS_ITG;
    float* ivv  = ws + WS_IVV;
    float* ivt  = ws + WS_IVT;
    int*   cols = (int*)(ws + WS_COLS);
    float* acc  = ws + WS_ACC;

    k_init<<<1, 16, 0, stream>>>(acc);

    k_invnorm<<<32, 256, 0, stream>>>(vg, ivg, 128);
    k_invnorm<<<32, 256, 0, stream>>>(tg, itg, 128);
    k_invnorm<<<4096, 256, 0, stream>>>(V, ivv, 16384);
    k_invnorm<<<4096, 256, 0, stream>>>(T, ivt, 16384);

    k_sim<<<128, 128, 0, stream>>>(vg, tg, ivg, itg, sim);
    k_global<<<1, 128, 0, stream>>>(sim, acc);

    k_cost<<<256, 256, 0, stream>>>(V, T, ivv, ivt, cost);
    k_hungarian<<<128, 64, 0, stream>>>(cost, cols);

    k_node<<<16384, 256, 0, stream>>>(V, T, cols, acc);
    k_graph<<<2048, 256, 0, stream>>>(Av, At, acc);

    k_final<<<1, 1, 0, stream>>>(acc, out);
}

// Round 7
// 453.470 us; speedup vs baseline: 2.7649x; 1.5413x over previous
//
#include <hip/hip_runtime.h>
#include <hip/hip_fp16.h>
#include <math.h>

#define TEMPERATURE 0.07f

// ---------------- ws layout (float offsets) ----------------
#define WS_COST    0          // 128*128*128 = 2097152
#define WS_SIM     2097152    // 16384
#define WS_COLS    2113536    // 16384 ints
#define WS_PNODE   2129920    // 2048 partials
#define WS_PGRAPH  2131968    // 2048 partials
#define WS_ACC     2134016    // 16 floats

// ---------------- sim[i][j] = cos(v_g[i], t_g[j]) / TEMP  (norms inline) -------
__global__ __launch_bounds__(128) void k_sim(const float* __restrict__ vg,
                                             const float* __restrict__ tg,
                                             float* __restrict__ sim) {
    int i = blockIdx.x, j = threadIdx.x;
    const float* vr = vg + (size_t)i * 1024;
    const float* tr = tg + (size_t)j * 1024;
    float acc = 0.0f, aa = 0.0f, bb = 0.0f;
    for (int k = 0; k < 1024; k += 4) {
        float4 a = *(const float4*)&vr[k];
        float4 b = *(const float4*)&tr[k];
        acc += a.x * b.x + a.y * b.y + a.z * b.z + a.w * b.w;
        aa  += a.x * a.x + a.y * a.y + a.z * a.z + a.w * a.w;
        bb  += b.x * b.x + b.y * b.y + b.z * b.z + b.w * b.w;
    }
    float iv = 1.0f / fmaxf(sqrtf(aa), 1e-12f);
    float it = 1.0f / fmaxf(sqrtf(bb), 1e-12f);
    sim[i * 128 + j] = acc * iv * it / TEMPERATURE;
}

// ---------------- L_global from sim (single block, 128 threads) ----------------
__global__ __launch_bounds__(128) void k_global(const float* __restrict__ sim,
                                                float* __restrict__ acc) {
    __shared__ float S[128 * 128];   // 64 KB: stage sim once, coalesced
    __shared__ float red[128];
    int t = threadIdx.x;
    for (int i = t * 4; i < 16384; i += 512)
        *(float4*)&S[i] = *(const float4*)&sim[i];
    __syncthreads();
    float m = -3e38f, m2 = -3e38f;
    for (int j = 0; j < 128; j++) {
        m = fmaxf(m, S[t * 128 + j]);
        m2 = fmaxf(m2, S[j * 128 + t]);
    }
    float s = 0.0f, s2 = 0.0f;
    for (int j = 0; j < 128; j++) {
        s += expf(S[t * 128 + j] - m);
        s2 += expf(S[j * 128 + t] - m2);
    }
    float contrib = 2.0f * S[t * 128 + t] - (m + logf(s)) - (m2 + logf(s2));
    red[t] = contrib;
    __syncthreads();
    for (int o = 64; o > 0; o >>= 1) {
        if (t < o) red[t] += red[t + o];
        __syncthreads();
    }
    if (t == 0) acc[0] = -red[0] / 256.0f;   // 0.5*(mean+mean), negated
}

// ---------------- cost[b][n][m] = 1 - cos(V[b,n], T[b,m])  (bf16 MFMA) --------
// Norms computed INLINE: ssq of raw f32 fragments accumulates during conversion;
// kq-group shfl_xor + epilogue bpermutes recover full-row inverse norms.
// dot uses raw bf16 values; cos = dot / (|v| |t|) with f32 norms (ref-like).
typedef __attribute__((ext_vector_type(8))) short short8v;
typedef __attribute__((ext_vector_type(4))) float f32x4;

__device__ __forceinline__ short bf16rne(float f) {
    unsigned int u = __float_as_uint(f);
    u += 0x7FFFu + ((u >> 16) & 1u);
    return (short)(u >> 16);
}
__device__ __forceinline__ short8v cvt8s(const float* __restrict__ p, float& ssq) {
    float4 x = *(const float4*)p;
    float4 y = *(const float4*)(p + 4);
    ssq += x.x * x.x + x.y * x.y + x.z * x.z + x.w * x.w
         + y.x * y.x + y.y * y.y + y.z * y.z + y.w * y.w;
    short8v r;
    r[0] = bf16rne(x.x); r[1] = bf16rne(x.y);
    r[2] = bf16rne(x.z); r[3] = bf16rne(x.w);
    r[4] = bf16rne(y.x); r[5] = bf16rne(y.y);
    r[6] = bf16rne(y.z); r[7] = bf16rne(y.w);
    return r;
}

__global__ __launch_bounds__(256) void k_cost(const float* __restrict__ V,
                                              const float* __restrict__ T,
                                              float* __restrict__ cost) {
    int b = blockIdx.x >> 1;
    int half = blockIdx.x & 1;
    int w = threadIdx.x >> 6;
    int lane = threadIdx.x & 63;
    int n0 = half * 64 + (w >> 1) * 32;   // wave's 32-row base
    int m0 = (w & 1) * 64;                // wave's 64-col base
    int ar = lane & 15, kq = lane >> 4;
    const float* Vb = V + (size_t)b * 131072;
    const float* Tb = T + (size_t)b * 131072;
    float qA0 = 0.0f, qA1 = 0.0f, qB0 = 0.0f, qB1 = 0.0f, qB2 = 0.0f, qB3 = 0.0f;
    f32x4 zero = {0.0f, 0.0f, 0.0f, 0.0f};
    f32x4 acc[2][4];
#pragma unroll
    for (int i = 0; i < 2; i++)
#pragma unroll
        for (int j = 0; j < 4; j++) acc[i][j] = zero;

    for (int k0 = 0; k0 < 1024; k0 += 32) {
        int ko = k0 + kq * 8;
        short8v a0 = cvt8s(&Vb[(size_t)(n0 + ar) * 1024 + ko], qA0);
        short8v a1 = cvt8s(&Vb[(size_t)(n0 + 16 + ar) * 1024 + ko], qA1);
        short8v b0 = cvt8s(&Tb[(size_t)(m0 + ar) * 1024 + ko], qB0);
        short8v b1 = cvt8s(&Tb[(size_t)(m0 + 16 + ar) * 1024 + ko], qB1);
        short8v b2 = cvt8s(&Tb[(size_t)(m0 + 32 + ar) * 1024 + ko], qB2);
        short8v b3 = cvt8s(&Tb[(size_t)(m0 + 48 + ar) * 1024 + ko], qB3);
        acc[0][0] = __builtin_amdgcn_mfma_f32_16x16x32_bf16(a0, b0, acc[0][0], 0, 0, 0);
        acc[0][1] = __builtin_amdgcn_mfma_f32_16x16x32_bf16(a0, b1, acc[0][1], 0, 0, 0);
        acc[0][2] = __builtin_amdgcn_mfma_f32_16x16x32_bf16(a0, b2, acc[0][2], 0, 0, 0);
        acc[0][3] = __builtin_amdgcn_mfma_f32_16x16x32_bf16(a0, b3, acc[0][3], 0, 0, 0);
        acc[1][0] = __builtin_amdgcn_mfma_f32_16x16x32_bf16(a1, b0, acc[1][0], 0, 0, 0);
        acc[1][1] = __builtin_amdgcn_mfma_f32_16x16x32_bf16(a1, b1, acc[1][1], 0, 0, 0);
        acc[1][2] = __builtin_amdgcn_mfma_f32_16x16x32_bf16(a1, b2, acc[1][2], 0, 0, 0);
        acc[1][3] = __builtin_amdgcn_mfma_f32_16x16x32_bf16(a1, b3, acc[1][3], 0, 0, 0);
    }
    // combine kq groups (lanes ar, ar+16, ar+32, ar+48 hold disjoint k-ranges)
    qA0 += __shfl_xor(qA0, 16); qA0 += __shfl_xor(qA0, 32);
    qA1 += __shfl_xor(qA1, 16); qA1 += __shfl_xor(qA1, 32);
    qB0 += __shfl_xor(qB0, 16); qB0 += __shfl_xor(qB0, 32);
    qB1 += __shfl_xor(qB1, 16); qB1 += __shfl_xor(qB1, 32);
    qB2 += __shfl_xor(qB2, 16); qB2 += __shfl_xor(qB2, 32);
    qB3 += __shfl_xor(qB3, 16); qB3 += __shfl_xor(qB3, 32);
    float invA0 = 1.0f / fmaxf(sqrtf(qA0), 1e-12f);   // V row n0+ar
    float invA1 = 1.0f / fmaxf(sqrtf(qA1), 1e-12f);   // V row n0+16+ar
    float invB[4];
    invB[0] = 1.0f / fmaxf(sqrtf(qB0), 1e-12f);       // T row m0+ar
    invB[1] = 1.0f / fmaxf(sqrtf(qB1), 1e-12f);
    invB[2] = 1.0f / fmaxf(sqrtf(qB2), 1e-12f);
    invB[3] = 1.0f / fmaxf(sqrtf(qB3), 1e-12f);
    // D layout: row = (lane>>4)*4 + r, col = lane&15  [m89 verified]
#pragma unroll
    for (int i = 0; i < 2; i++) {
        float ia[4];
#pragma unroll
        for (int r = 0; r < 4; r++)
            ia[r] = __shfl(i ? invA1 : invA0, kq * 4 + r);   // inv norm of row n0+i*16+kq*4+r
#pragma unroll
        for (int j = 0; j < 4; j++)
#pragma unroll
            for (int r = 0; r < 4; r++) {
                int rowi = n0 + i * 16 + kq * 4 + r;
                int colj = m0 + j * 16 + ar;
                cost[((size_t)b * 128 + rowi) * 128 + colj] = 1.0f - acc[i][j][r] * ia[r] * invB[j];
            }
    }
}

// ================= Hungarian: LAPJV (colred + 2x ARR + augmentation) ============
// One wave per batch problem, 128 blocks. Lane owns columns {lane, lane+64} and
// rows {lane, lane+64}. Cost packed fp16 half2 in LDS (one b32 read per row).
#define HUNG_INF 3.0e38f

__device__ __forceinline__ int rdlane_i(int v, int l) {
    return __builtin_amdgcn_readlane(v, l);
}
__device__ __forceinline__ float rdlane_f(float v, int l) {
    return __int_as_float(__builtin_amdgcn_readlane(__float_as_int(v), l));
}

// full-wave u32 min via DPP (identity UINT_MAX); result valid in lane 63
__device__ __forceinline__ unsigned int dpp_umin_wave(unsigned int x) {
    int o;
    o = __builtin_amdgcn_update_dpp(-1, (int)x, 0x111, 0xF, 0xF, false); // row_shr:1
    x = (x < (unsigned int)o) ? x : (unsigned int)o;
    o = __builtin_amdgcn_update_dpp(-1, (int)x, 0x112, 0xF, 0xF, false); // row_shr:2
    x = (x < (unsigned int)o) ? x : (unsigned int)o;
    o = __builtin_amdgcn_update_dpp(-1, (int)x, 0x114, 0xF, 0xF, false); // row_shr:4
    x = (x < (unsigned int)o) ? x : (unsigned int)o;
    o = __builtin_amdgcn_update_dpp(-1, (int)x, 0x118, 0xF, 0xF, false); // row_shr:8
    x = (x < (unsigned int)o) ? x : (unsigned int)o;
    o = __builtin_amdgcn_update_dpp(-1, (int)x, 0x142, 0xF, 0xF, false); // row_bcast:15
    x = (x < (unsigned int)o) ? x : (unsigned int)o;
    o = __builtin_amdgcn_update_dpp(-1, (int)x, 0x143, 0xF, 0xF, false); // row_bcast:31
    x = (x < (unsigned int)o) ? x : (unsigned int)o;
    return x;
}

__device__ __forceinline__ unsigned int pack_h2(float a, float b) {
    unsigned int ua = (unsigned int)__half_as_ushort(__float2half(a));
    unsigned int ub = (unsigned int)__half_as_ushort(__float2half(b));
    return ua | (ub << 16);
}
__device__ __forceinline__ float h2_lo(unsigned int u) {
    return __half2float(__ushort_as_half((unsigned short)(u & 0xFFFFu)));
}
__device__ __forceinline__ float h2_hi(unsigned int u) {
    return __half2float(__ushort_as_half((unsigned short)(u >> 16)));
}
// sortable key: biased value bits (top 25) | column index (low 7). val >= -eps.
__device__ __forceinline__ unsigned int vkey(float v, int idx) {
    return (__float_as_uint(v + 1.0f) & 0xFFFFFF80u) | (unsigned int)idx;
}

__global__ __launch_bounds__(64) void k_hungarian(const float* __restrict__ cost,
                                                  int* __restrict__ cols) {
    __shared__ unsigned int P[128 * 64];   // 32 KB packed fp16 cost
    __shared__ int freelist[136];
    int b = blockIdx.x;
    int lane = threadIdx.x;
    const float* C = cost + (size_t)b * 16384;
#pragma unroll 4
    for (int r = 0; r < 128; ++r)
        P[r * 64 + lane] = pack_h2(C[r * 128 + lane], C[r * 128 + 64 + lane]);
    __syncthreads();

    // ---- phase 1: column reduction (v[j] = min_i c[i][j], argmin keeps lowest i) ----
    float vA = HUNG_INF, vB = HUNG_INF;   // col duals: v[lane], v[lane+64]
    int yA = 0, yB = 0;                   // argmin rows
    for (int r = 0; r < 128; ++r) {
        unsigned int pk = P[r * 64 + lane];
        float a = h2_lo(pk), bb = h2_hi(pk);
        if (a < vA) { vA = a; yA = r; }
        if (bb < vB) { vB = bb; yB = r; }
    }
    int p0 = -1, p1 = -1;     // row matched to col lane / lane+64
    int x0 = -1, x1 = -1;     // col matched to row lane / lane+64 (preprocessing only)
    float u0 = 0.0f, u1 = 0.0f;   // row duals
    for (int j = 127; j >= 0; --j) {   // descending, like _ccrrt_dense
        int yi = rdlane_i(j >= 64 ? yB : yA, j & 63);
        int xi = rdlane_i(yi >= 64 ? x1 : x0, yi & 63);
        if (xi < 0) {
            if (lane == (yi & 63)) { if (yi < 64) x0 = j; else x1 = j; }
            if (lane == (j & 63)) { if (j < 64) p0 = yi; else p1 = yi; }
        }
    }
    // ---- build free-row list (ascending row order) ----
    unsigned long long fm0 = __ballot(x0 < 0);
    unsigned long long fm1 = __ballot(x1 < 0);
    int half0 = __popcll(fm0);
    int nfree = half0 + __popcll(fm1);
    if (x0 < 0) freelist[__popcll(fm0 & ((1ull << lane) - 1))] = lane;
    if (x1 < 0) freelist[half0 + __popcll(fm1 & ((1ull << lane) - 1))] = lane + 64;
    __syncthreads();

    // ---- phase 2: augmenting row reduction x2 (lap _carr_dense semantics) ----
    for (int pass = 0; pass < 2 && nfree > 0; ++pass) {
        int cur = 0, nnew = 0, rr = 0;
        while (cur < nfree) {
            int fi = freelist[cur]; cur++;
            rr++;
            if (rr >= 600 || rr >= cur * 128) {
                // safety drain: give up on fi; phase 3 (exact) will handle it
                if (lane == 0) freelist[nnew] = fi;
                nnew++;
                continue;
            }
            unsigned int pk = P[fi * 64 + lane];
            float rc0 = h2_lo(pk) - vA;
            float rc1 = h2_hi(pk) - vB;
            unsigned int k0 = vkey(rc0, lane);
            unsigned int k1 = vkey(rc1, lane + 64);
            unsigned int km = dpp_umin_wave(k0 < k1 ? k0 : k1);
            int j1 = (int)((unsigned int)rdlane_i((int)km, 63) & 127u);
            float vmin = rdlane_f(j1 >= 64 ? rc1 : rc0, j1 & 63);   // exact
            unsigned int k0m = (j1 == lane) ? 0xFFFFFFFFu : k0;      // mask min ELEMENT
            unsigned int k1m = (j1 == lane + 64) ? 0xFFFFFFFFu : k1;
            unsigned int km2 = dpp_umin_wave(k0m < k1m ? k0m : k1m);
            int j2 = (int)((unsigned int)rdlane_i((int)km2, 63) & 127u);
            float vsec = rdlane_f(j2 >= 64 ? rc1 : rc0, j2 & 63);   // exact
            int i0 = rdlane_i(j1 >= 64 ? p1 : p0, j1 & 63);
            bool lowers = vmin < vsec;
            if (lowers) {
                if (lane == (j1 & 63)) {
                    if (j1 < 64) vA -= (vsec - vmin); else vB -= (vsec - vmin);
                }
            } else if (i0 >= 0) {        // tie: switch to second-min column
                j1 = j2;
                i0 = rdlane_i(j1 >= 64 ? p1 : p0, j1 & 63);
            }
            if (i0 >= 0) {
                if (lowers) { cur--; if (lane == 0) freelist[cur] = i0; }  // reprocess now
                else { if (lane == 0) freelist[nnew] = i0; nnew++; }       // next pass
            }
            // assign fi -> j1; u[fi] = vsec keeps the matched edge tight & duals feasible
            if (lane == (j1 & 63)) { if (j1 < 64) p0 = fi; else p1 = fi; }
            if (lane == (fi & 63)) { if (fi < 64) u0 = vsec; else u1 = vsec; }
        }
        nfree = nnew;
    }

    // ---- phase 3: exact Dijkstra augmentation for remaining free rows ----
    for (int fx = 0; fx < nfree; ++fx) {
        int row = freelist[fx];
        float minv0 = HUNG_INF, minv1 = HUNG_INF;
        int way0 = 128, way1 = 128;
        bool used0 = false, used1 = false;
        bool intree0 = (row < 64) && (lane == row);
        bool intree1 = (row >= 64) && (lane == row - 64);
        int j0 = 128;        // virtual root column
        int i0r = row;       // row to expand
        while (true) {
            float ui = rdlane_f(i0r >= 64 ? u1 : u0, i0r & 63);
            unsigned int pk = P[i0r * 64 + lane];
            float cur0 = h2_lo(pk) - ui - vA;
            float cur1 = h2_hi(pk) - ui - vB;
            if (!used0 && cur0 < minv0) { minv0 = cur0; way0 = j0; }
            if (!used1 && cur1 < minv1) { minv1 = cur1; way1 = j0; }
            float cand0 = used0 ? HUNG_INF : minv0;
            float cand1 = used1 ? HUNG_INF : minv1;
            unsigned int k0 = vkey(cand0, lane);
            unsigned int k1 = vkey(cand1, lane + 64);
            unsigned int km = dpp_umin_wave(k0 < k1 ? k0 : k1);
            unsigned int kmin = (unsigned int)rdlane_i((int)km, 63);
            int j1 = (int)(kmin & 127u);
            float delta = __uint_as_float(kmin & 0xFFFFFF80u) - 1.0f;  // <= exact min
            if (used0) vA -= delta; else minv0 -= delta;
            if (used1) vB -= delta; else minv1 -= delta;
            if (intree0) u0 += delta;
            if (intree1) u1 += delta;
            int pj = rdlane_i(j1 >= 64 ? p1 : p0, j1 & 63);
            if (pj >= 0) {
                if (lane == (j1 & 63)) { if (j1 >= 64) used1 = true; else used0 = true; }
                if (lane == (pj & 63)) { if (pj < 64) intree0 = true; else intree1 = true; }
                j0 = j1;
                i0r = pj;
            } else {
                // augment along alternating path from j1
                int j = j1;
                while (j != 128) {
                    int w = rdlane_i(j >= 64 ? way1 : way0, j & 63);
                    int pw = (w == 128) ? row : rdlane_i(w >= 64 ? p1 : p0, w & 63);
                    if (lane == (j & 63)) { if (j >= 64) p1 = pw; else p0 = pw; }
                    j = w;
                }
                break;
            }
        }
    }
    // p[j] = row matched to column j  ->  cols[row] = j
    cols[b * 128 + p0] = lane;
    cols[b * 128 + p1] = lane + 64;
}

// ---------------- node MSE: 2048 blocks, grid-stride, partial per block --------
__global__ __launch_bounds__(256) void k_node(const float* __restrict__ V,
                                              const float* __restrict__ T,
                                              const int* __restrict__ cols,
                                              float* __restrict__ pn) {
    int t = threadIdx.x;
    float s = 0.0f;
    for (int bn = blockIdx.x; bn < 16384; bn += 2048) {
        int b = bn >> 7, n = bn & 127;
        int c = cols[bn];
        const float* vr = V + ((size_t)b * 128 + n) * 1024;
        const float* tr = T + ((size_t)b * 128 + c) * 1024;
        float4 a = *(const float4*)&vr[t * 4];
        float4 bb = *(const float4*)&tr[t * 4];
        float dx = a.x - bb.x, dy = a.y - bb.y, dz = a.z - bb.z, dw = a.w - bb.w;
        s += dx * dx + dy * dy + dz * dz + dw * dw;
    }
#pragma unroll
    for (int off = 32; off > 0; off >>= 1) s += __shfl_xor(s, off);
    __shared__ float wsum[4];
    if ((t & 63) == 0) wsum[t >> 6] = s;
    __syncthreads();
    if (t == 0) pn[blockIdx.x] = wsum[0] + wsum[1] + wsum[2] + wsum[3];
}

// ---------------- graph MSE: 2048 blocks, partial per block --------------------
__global__ __launch_bounds__(256) void k_graph(const float* __restrict__ Av,
                                               const float* __restrict__ At,
                                               float* __restrict__ pg) {
    size_t idx = ((size_t)blockIdx.x * 256 + threadIdx.x) * 4;
    float4 a = *(const float4*)&Av[idx];
    float4 bb = *(const float4*)&At[idx];
    float dx = a.x - bb.x, dy = a.y - bb.y, dz = a.z - bb.z, dw = a.w - bb.w;
    float s = dx * dx + dy * dy + dz * dz + dw * dw;
#pragma unroll
    for (int off = 32; off > 0; off >>= 1) s += __shfl_xor(s, off);
    __shared__ float wsum[4];
    int t = threadIdx.x;
    if ((t & 63) == 0) wsum[t >> 6] = s;
    __syncthreads();
    if (t == 0) pg[blockIdx.x] = wsum[0] + wsum[1] + wsum[2] + wsum[3];
}

// ---------------- finalize: reduce partials, emit 4 outputs --------------------
__global__ __launch_bounds__(256) void k_final(const float* __restrict__ acc,
                                               const float* __restrict__ pn,
                                               const float* __restrict__ pg,
                                               float* __restrict__ out) {
    __shared__ float r1[256], r2[256];
    int t = threadIdx.x;
    float sn = 0.0f, sg = 0.0f;
    for (int q = t; q < 2048; q += 256) { sn += pn[q]; sg += pg[q]; }
    r1[t] = sn; r2[t] = sg;
    __syncthreads();
    for (int o = 128; o > 0; o >>= 1) {
        if (t < o) { r1[t] += r1[t + o]; r2[t] += r2[t + o]; }
        __syncthreads();
    }
    if (t == 0) {
        float lg = acc[0];
        float ln = r1[0] / 16777216.0f;   // 128*128*1024
        float lgr = r2[0] / 2097152.0f;   // 128*128*128
        out[0] = lg + ln + lgr;
        out[1] = lg;
        out[2] = ln;
        out[3] = lgr;
    }
}

extern "C" void kernel_launch(void* const* d_in, const int* in_sizes, int n_in,
                              void* d_out, int out_size, void* d_ws, size_t ws_size,
                              hipStream_t stream) {
    const float* vg = (const float*)d_in[0];
    const float* tg = (const float*)d_in[1];
    const float* V  = (const float*)d_in[2];
    const float* T  = (const float*)d_in[3];
    const float* Av = (const float*)d_in[4];
    const float* At = (const float*)d_in[5];
    float* out = (float*)d_out;
    float* ws = (float*)d_ws;

    float* cost = ws + WS_COST;
    float* sim  = ws + WS_SIM;
    int*   cols = (int*)(ws + WS_COLS);
    float* pn   = ws + WS_PNODE;
    float* pg   = ws + WS_PGRAPH;
    float* acc  = ws + WS_ACC;

    k_cost<<<256, 256, 0, stream>>>(V, T, cost);
    k_sim<<<128, 128, 0, stream>>>(vg, tg, sim);
    k_global<<<1, 128, 0, stream>>>(sim, acc);
    k_hungarian<<<128, 64, 0, stream>>>(cost, cols);
    k_node<<<2048, 256, 0, stream>>>(V, T, cols, pn);
    k_graph<<<2048, 256, 0, stream>>>(Av, At, pg);
    k_final<<<1, 256, 0, stream>>>(acc, pn, pg, out);
}

// Round 8
// 405.937 us; speedup vs baseline: 3.0887x; 1.1171x over previous
//
#include <hip/hip_runtime.h>
#include <hip/hip_fp16.h>
#include <math.h>

#define TEMPERATURE 0.07f

// ---------------- ws layout (float offsets) ----------------
#define WS_COST    0          // 128*128*128 = 2097152
#define WS_SIM     2097152    // 16384
#define WS_COLS    2113536    // 16384 ints
#define WS_RNV     2129920    // 16384 |V| row norms
#define WS_RNT     2146304    // 16384 |T| row norms
#define WS_PNODE   2162688    // 128 partials
#define WS_PGRAPH  2162816    // 128 partials
#define WS_ACC     2162944    // 16 floats

// =================== shared MFMA cosine-tile machinery ========================
typedef __attribute__((ext_vector_type(8))) short short8v;
typedef __attribute__((ext_vector_type(4))) float f32x4;

__device__ __forceinline__ short bf16rne(float f) {
    unsigned int u = __float_as_uint(f);
    u += 0x7FFFu + ((u >> 16) & 1u);
    return (short)(u >> 16);
}
__device__ __forceinline__ short8v cvt8s(const float* __restrict__ p, float& ssq) {
    float4 x = *(const float4*)p;
    float4 y = *(const float4*)(p + 4);
    ssq += x.x * x.x + x.y * x.y + x.z * x.z + x.w * x.w
         + y.x * y.x + y.y * y.y + y.z * y.z + y.w * y.w;
    short8v r;
    r[0] = bf16rne(x.x); r[1] = bf16rne(x.y);
    r[2] = bf16rne(x.z); r[3] = bf16rne(x.w);
    r[4] = bf16rne(y.x); r[5] = bf16rne(y.y);
    r[6] = bf16rne(y.z); r[7] = bf16rne(y.w);
    return r;
}

// 64x128 cosine tile (half selects which 64 rows). COSTMODE: out = 1-cos and
// export row norms. !COSTMODE: out = cos/TEMP (for sim).
template<bool COSTMODE>
__device__ __forceinline__ void cos_tile(const float* __restrict__ Vb,
                                         const float* __restrict__ Tb,
                                         int half, int tid,
                                         float* __restrict__ outp,
                                         float* __restrict__ rnV,
                                         float* __restrict__ rnT) {
    int w = tid >> 6;
    int lane = tid & 63;
    int n0 = half * 64 + (w >> 1) * 32;
    int m0 = (w & 1) * 64;
    int ar = lane & 15, kq = lane >> 4;
    float qA0 = 0.0f, qA1 = 0.0f, qB0 = 0.0f, qB1 = 0.0f, qB2 = 0.0f, qB3 = 0.0f;
    f32x4 zero = {0.0f, 0.0f, 0.0f, 0.0f};
    f32x4 acc[2][4];
#pragma unroll
    for (int i = 0; i < 2; i++)
#pragma unroll
        for (int j = 0; j < 4; j++) acc[i][j] = zero;

    for (int k0 = 0; k0 < 1024; k0 += 32) {
        int ko = k0 + kq * 8;
        short8v a0 = cvt8s(&Vb[(size_t)(n0 + ar) * 1024 + ko], qA0);
        short8v a1 = cvt8s(&Vb[(size_t)(n0 + 16 + ar) * 1024 + ko], qA1);
        short8v b0 = cvt8s(&Tb[(size_t)(m0 + ar) * 1024 + ko], qB0);
        short8v b1 = cvt8s(&Tb[(size_t)(m0 + 16 + ar) * 1024 + ko], qB1);
        short8v b2 = cvt8s(&Tb[(size_t)(m0 + 32 + ar) * 1024 + ko], qB2);
        short8v b3 = cvt8s(&Tb[(size_t)(m0 + 48 + ar) * 1024 + ko], qB3);
        acc[0][0] = __builtin_amdgcn_mfma_f32_16x16x32_bf16(a0, b0, acc[0][0], 0, 0, 0);
        acc[0][1] = __builtin_amdgcn_mfma_f32_16x16x32_bf16(a0, b1, acc[0][1], 0, 0, 0);
        acc[0][2] = __builtin_amdgcn_mfma_f32_16x16x32_bf16(a0, b2, acc[0][2], 0, 0, 0);
        acc[0][3] = __builtin_amdgcn_mfma_f32_16x16x32_bf16(a0, b3, acc[0][3], 0, 0, 0);
        acc[1][0] = __builtin_amdgcn_mfma_f32_16x16x32_bf16(a1, b0, acc[1][0], 0, 0, 0);
        acc[1][1] = __builtin_amdgcn_mfma_f32_16x16x32_bf16(a1, b1, acc[1][1], 0, 0, 0);
        acc[1][2] = __builtin_amdgcn_mfma_f32_16x16x32_bf16(a1, b2, acc[1][2], 0, 0, 0);
        acc[1][3] = __builtin_amdgcn_mfma_f32_16x16x32_bf16(a1, b3, acc[1][3], 0, 0, 0);
    }
    qA0 += __shfl_xor(qA0, 16); qA0 += __shfl_xor(qA0, 32);
    qA1 += __shfl_xor(qA1, 16); qA1 += __shfl_xor(qA1, 32);
    qB0 += __shfl_xor(qB0, 16); qB0 += __shfl_xor(qB0, 32);
    qB1 += __shfl_xor(qB1, 16); qB1 += __shfl_xor(qB1, 32);
    qB2 += __shfl_xor(qB2, 16); qB2 += __shfl_xor(qB2, 32);
    qB3 += __shfl_xor(qB3, 16); qB3 += __shfl_xor(qB3, 32);
    if (COSTMODE && kq == 0) {
        rnV[n0 + ar]      = sqrtf(qA0);
        rnV[n0 + 16 + ar] = sqrtf(qA1);
        rnT[m0 + ar]      = sqrtf(qB0);
        rnT[m0 + 16 + ar] = sqrtf(qB1);
        rnT[m0 + 32 + ar] = sqrtf(qB2);
        rnT[m0 + 48 + ar] = sqrtf(qB3);
    }
    float invA0 = 1.0f / fmaxf(sqrtf(qA0), 1e-12f);
    float invA1 = 1.0f / fmaxf(sqrtf(qA1), 1e-12f);
    float invB[4];
    invB[0] = 1.0f / fmaxf(sqrtf(qB0), 1e-12f);
    invB[1] = 1.0f / fmaxf(sqrtf(qB1), 1e-12f);
    invB[2] = 1.0f / fmaxf(sqrtf(qB2), 1e-12f);
    invB[3] = 1.0f / fmaxf(sqrtf(qB3), 1e-12f);
    // D layout: row = (lane>>4)*4 + r, col = lane&15
#pragma unroll
    for (int i = 0; i < 2; i++) {
        float ia[4];
#pragma unroll
        for (int r = 0; r < 4; r++)
            ia[r] = __shfl(i ? invA1 : invA0, kq * 4 + r);
#pragma unroll
        for (int j = 0; j < 4; j++)
#pragma unroll
            for (int r = 0; r < 4; r++) {
                int rowi = n0 + i * 16 + kq * 4 + r;
                int colj = m0 + j * 16 + ar;
                float cs = acc[i][j][r] * ia[r] * invB[j];
                outp[(size_t)rowi * 128 + colj] =
                    COSTMODE ? (1.0f - cs) : (cs * (1.0f / TEMPERATURE));
            }
    }
}

// ---------------- cost + row norms ----------------
__global__ __launch_bounds__(256) void k_cost(const float* __restrict__ V,
                                              const float* __restrict__ T,
                                              float* __restrict__ cost,
                                              float* __restrict__ rnV,
                                              float* __restrict__ rnT) {
    int b = blockIdx.x >> 1;
    int half = blockIdx.x & 1;
    cos_tile<true>(V + (size_t)b * 131072, T + (size_t)b * 131072, half, threadIdx.x,
                   cost + (size_t)b * 16384, rnV + b * 128, rnT + b * 128);
}

// =================== Hungarian helpers ========================================
#define HUNG_INF 3.0e38f

__device__ __forceinline__ int rdlane_i(int v, int l) {
    return __builtin_amdgcn_readlane(v, l);
}
__device__ __forceinline__ float rdlane_f(float v, int l) {
    return __int_as_float(__builtin_amdgcn_readlane(__float_as_int(v), l));
}

__device__ __forceinline__ unsigned int dpp_umin_wave(unsigned int x) {
    int o;
    o = __builtin_amdgcn_update_dpp(-1, (int)x, 0x111, 0xF, 0xF, false);
    x = (x < (unsigned int)o) ? x : (unsigned int)o;
    o = __builtin_amdgcn_update_dpp(-1, (int)x, 0x112, 0xF, 0xF, false);
    x = (x < (unsigned int)o) ? x : (unsigned int)o;
    o = __builtin_amdgcn_update_dpp(-1, (int)x, 0x114, 0xF, 0xF, false);
    x = (x < (unsigned int)o) ? x : (unsigned int)o;
    o = __builtin_amdgcn_update_dpp(-1, (int)x, 0x118, 0xF, 0xF, false);
    x = (x < (unsigned int)o) ? x : (unsigned int)o;
    o = __builtin_amdgcn_update_dpp(-1, (int)x, 0x142, 0xF, 0xF, false);
    x = (x < (unsigned int)o) ? x : (unsigned int)o;
    o = __builtin_amdgcn_update_dpp(-1, (int)x, 0x143, 0xF, 0xF, false);
    x = (x < (unsigned int)o) ? x : (unsigned int)o;
    return x;
}

// paired two-smallest DPP stage (exact at lane 63: merge windows are disjoint)
template<int CTRL>
__device__ __forceinline__ void dpp2min(unsigned int& a, unsigned int& b) {
    unsigned int ao = (unsigned int)__builtin_amdgcn_update_dpp(-1, (int)a, CTRL, 0xF, 0xF, false);
    unsigned int bo = (unsigned int)__builtin_amdgcn_update_dpp(-1, (int)b, CTRL, 0xF, 0xF, false);
    unsigned int hi = a > ao ? a : ao;
    a = a < ao ? a : ao;
    b = b < bo ? b : bo;
    b = b < hi ? b : hi;
}

__device__ __forceinline__ unsigned int pack_h2(float a, float b) {
    unsigned int ua = (unsigned int)__half_as_ushort(__float2half(a));
    unsigned int ub = (unsigned int)__half_as_ushort(__float2half(b));
    return ua | (ub << 16);
}
__device__ __forceinline__ float h2_lo(unsigned int u) {
    return __half2float(__ushort_as_half((unsigned short)(u & 0xFFFFu)));
}
__device__ __forceinline__ float h2_hi(unsigned int u) {
    return __half2float(__ushort_as_half((unsigned short)(u >> 16)));
}
// sortable key: biased value bits (top 25) | column index (low 7). val >= -eps.
__device__ __forceinline__ unsigned int vkey(float v, int idx) {
    return (__float_as_uint(v + 1.0f) & 0xFFFFFF80u) | (unsigned int)idx;
}

// =================== uber-kernel: hungarian + sim + graph =====================
// blocks 0..127: LAPJV per batch problem (wave 0 after 256-thread staging)
// blocks 128..129: sim = cos(vg,tg)/TEMP via MFMA (two 64-row halves)
// blocks 130..257: graph-MSE partials (fill CUs idle during hungarian)
__global__ __launch_bounds__(256) void k_main(const float* __restrict__ cost,
                                              int* __restrict__ cols,
                                              const float* __restrict__ vg,
                                              const float* __restrict__ tg,
                                              float* __restrict__ sim,
                                              const float* __restrict__ Av,
                                              const float* __restrict__ At,
                                              float* __restrict__ pg) {
    int bid = blockIdx.x;
    int t = threadIdx.x;
    __shared__ unsigned int P[8192];     // 32 KB packed fp16 cost
    __shared__ int freelist[136];
    __shared__ float wsumg[4];

    if (bid >= 130) {                    // ---- graph MSE partial ----
        int idx = bid - 130;
        float s = 0.0f;
        for (int it = 0; it < 16; ++it) {
            size_t off = (((size_t)idx * 16 + it) * 256 + t) * 4;
            float4 a = *(const float4*)&Av[off];
            float4 bb = *(const float4*)&At[off];
            float dx = a.x - bb.x, dy = a.y - bb.y, dz = a.z - bb.z, dw = a.w - bb.w;
            s += dx * dx + dy * dy + dz * dz + dw * dw;
        }
#pragma unroll
        for (int off = 32; off > 0; off >>= 1) s += __shfl_xor(s, off);
        if ((t & 63) == 0) wsumg[t >> 6] = s;
        __syncthreads();
        if (t == 0) pg[idx] = wsumg[0] + wsumg[1] + wsumg[2] + wsumg[3];
        return;
    }
    if (bid >= 128) {                    // ---- sim via MFMA ----
        cos_tile<false>(vg, tg, bid - 128, t, sim, (float*)0, (float*)0);
        return;
    }

    // ---- hungarian: stage with all 256 threads, then wave 0 solves ----
    int b = bid;
    const float* C = cost + (size_t)b * 16384;
    for (int i = t; i < 8192; i += 256) {
        int r = i >> 6, l = i & 63;
        P[i] = pack_h2(C[r * 128 + l], C[r * 128 + 64 + l]);
    }
    __syncthreads();
    if (t >= 64) return;                 // no barriers beyond this point
    int lane = t;

    // ---- phase 1: column reduction ----
    float vA = HUNG_INF, vB = HUNG_INF;
    int yA = 0, yB = 0;
    for (int r = 0; r < 128; ++r) {
        unsigned int pk = P[r * 64 + lane];
        float a = h2_lo(pk), bb = h2_hi(pk);
        if (a < vA) { vA = a; yA = r; }
        if (bb < vB) { vB = bb; yB = r; }
    }
    int p0 = -1, p1 = -1;     // row matched to col lane / lane+64
    int x0 = -1, x1 = -1;     // col matched to row lane / lane+64
    float u0 = 0.0f, u1 = 0.0f;
    for (int j = 127; j >= 0; --j) {
        int yi = rdlane_i(j >= 64 ? yB : yA, j & 63);
        int xi = rdlane_i(yi >= 64 ? x1 : x0, yi & 63);
        if (xi < 0) {
            if (lane == (yi & 63)) { if (yi < 64) x0 = j; else x1 = j; }
            if (lane == (j & 63)) { if (j < 64) p0 = yi; else p1 = yi; }
        }
    }

    // ---- phase 1.5: reduction transfer (JV _ccrrt second half) ----
    // For matched row i->j1: min2 = min_{j!=j1}(c[i][j]-v[j]); v[j1]-=min2; u[i]=min2.
    // Keeps duals feasible and the matched edge tight (truncation-consistent).
    {
        unsigned int pkc = P[lane];
        for (int i = 0; i < 128; ++i) {
            unsigned int pkn = (i < 127) ? P[(i + 1) * 64 + lane] : 0u;
            int j1 = rdlane_i(i >= 64 ? x1 : x0, i & 63);
            if (j1 >= 0) {
                float rc0 = h2_lo(pkc) - vA;
                float rc1 = h2_hi(pkc) - vB;
                unsigned int k0 = (j1 < 64 && lane == j1) ? 0xFFFFFFFFu : vkey(rc0, lane);
                unsigned int k1 = (j1 >= 64 && lane == (j1 - 64)) ? 0xFFFFFFFFu : vkey(rc1, lane + 64);
                unsigned int km = dpp_umin_wave(k0 < k1 ? k0 : k1);
                unsigned int ka = (unsigned int)rdlane_i((int)km, 63);
                float min2 = __uint_as_float(ka & 0xFFFFFF80u) - 1.0f;
                if (lane == (j1 & 63)) { if (j1 < 64) vA -= min2; else vB -= min2; }
                if (lane == (i & 63)) { if (i < 64) u0 = min2; else u1 = min2; }
            }
            pkc = pkn;
        }
    }

    // ---- free-row list ----
    unsigned long long fm0 = __ballot(x0 < 0);
    unsigned long long fm1 = __ballot(x1 < 0);
    int half0 = __popcll(fm0);
    int nfree = half0 + __popcll(fm1);
    if (x0 < 0) freelist[__popcll(fm0 & ((1ull << lane) - 1))] = lane;
    if (x1 < 0) freelist[half0 + __popcll(fm1 & ((1ull << lane) - 1))] = lane + 64;

    // ---- phase 2: augmenting row reduction x2 (paired two-smallest tree) ----
    for (int pass = 0; pass < 2 && nfree > 0; ++pass) {
        int cur = 0, nnew = 0, rr = 0;
        while (cur < nfree) {
            int fi = freelist[cur]; cur++;
            rr++;
            if (rr >= 600 || rr >= cur * 128) {
                if (lane == 0) freelist[nnew] = fi;
                nnew++;
                continue;
            }
            unsigned int pk = P[fi * 64 + lane];
            float rc0 = h2_lo(pk) - vA;
            float rc1 = h2_hi(pk) - vB;
            unsigned int k0 = vkey(rc0, lane);
            unsigned int k1 = vkey(rc1, lane + 64);
            unsigned int a = k0 < k1 ? k0 : k1;
            unsigned int bk = k0 < k1 ? k1 : k0;
            dpp2min<0x111>(a, bk); dpp2min<0x112>(a, bk); dpp2min<0x114>(a, bk);
            dpp2min<0x118>(a, bk); dpp2min<0x142>(a, bk); dpp2min<0x143>(a, bk);
            unsigned int ka = (unsigned int)rdlane_i((int)a, 63);
            unsigned int kb = (unsigned int)rdlane_i((int)bk, 63);
            int j1 = (int)(ka & 127u);
            float vmin = __uint_as_float(ka & 0xFFFFFF80u) - 1.0f;
            float vsec = __uint_as_float(kb & 0xFFFFFF80u) - 1.0f;
            bool lowers = (ka & 0xFFFFFF80u) < (kb & 0xFFFFFF80u);
            int i0 = rdlane_i(j1 >= 64 ? p1 : p0, j1 & 63);
            if (lowers) {
                if (lane == (j1 & 63)) {
                    if (j1 < 64) vA -= (vsec - vmin); else vB -= (vsec - vmin);
                }
            } else if (i0 >= 0) {
                j1 = (int)(kb & 127u);
                i0 = rdlane_i(j1 >= 64 ? p1 : p0, j1 & 63);
            }
            if (i0 >= 0) {
                if (lowers) { cur--; if (lane == 0) freelist[cur] = i0; }
                else { if (lane == 0) freelist[nnew] = i0; nnew++; }
            }
            if (lane == (j1 & 63)) { if (j1 < 64) p0 = fi; else p1 = fi; }
            if (lane == (fi & 63)) { if (fi < 64) u0 = vsec; else u1 = vsec; }
        }
        nfree = nnew;
    }

    // ---- phase 3: exact Dijkstra augmentation for remaining free rows ----
    for (int fx = 0; fx < nfree; ++fx) {
        int row = freelist[fx];
        float minv0 = HUNG_INF, minv1 = HUNG_INF;
        int way0 = 128, way1 = 128;
        bool used0 = false, used1 = false;
        bool intree0 = (row < 64) && (lane == row);
        bool intree1 = (row >= 64) && (lane == row - 64);
        int j0 = 128;
        int i0r = row;
        while (true) {
            float ui = rdlane_f(i0r >= 64 ? u1 : u0, i0r & 63);
            unsigned int pk = P[i0r * 64 + lane];
            float cur0 = h2_lo(pk) - ui - vA;
            float cur1 = h2_hi(pk) - ui - vB;
            if (!used0 && cur0 < minv0) { minv0 = cur0; way0 = j0; }
            if (!used1 && cur1 < minv1) { minv1 = cur1; way1 = j0; }
            float cand0 = used0 ? HUNG_INF : minv0;
            float cand1 = used1 ? HUNG_INF : minv1;
            unsigned int k0 = vkey(cand0, lane);
            unsigned int k1 = vkey(cand1, lane + 64);
            unsigned int km = dpp_umin_wave(k0 < k1 ? k0 : k1);
            unsigned int kmin = (unsigned int)rdlane_i((int)km, 63);
            int j1 = (int)(kmin & 127u);
            float delta = __uint_as_float(kmin & 0xFFFFFF80u) - 1.0f;
            if (used0) vA -= delta; else minv0 -= delta;
            if (used1) vB -= delta; else minv1 -= delta;
            if (intree0) u0 += delta;
            if (intree1) u1 += delta;
            int pj = rdlane_i(j1 >= 64 ? p1 : p0, j1 & 63);
            if (pj >= 0) {
                if (lane == (j1 & 63)) { if (j1 >= 64) used1 = true; else used0 = true; }
                if (lane == (pj & 63)) { if (pj < 64) intree0 = true; else intree1 = true; }
                j0 = j1;
                i0r = pj;
            } else {
                int j = j1;
                while (j != 128) {
                    int w = rdlane_i(j >= 64 ? way1 : way0, j & 63);
                    int pw = (w == 128) ? row : rdlane_i(w >= 64 ? p1 : p0, w & 63);
                    if (lane == (j & 63)) { if (j >= 64) p1 = pw; else p0 = pw; }
                    j = w;
                }
                break;
            }
        }
    }
    cols[b * 128 + p0] = lane;
    cols[b * 128 + p1] = lane + 64;
}

// ---------------- node MSE (reconstructed from norms+cost) + L_global ----------
// blocks 0..127: node partial for batch b. block 128: L_global.
__global__ __launch_bounds__(128) void k_gn(const float* __restrict__ rnV,
                                            const float* __restrict__ rnT,
                                            const float* __restrict__ cost,
                                            const int* __restrict__ cols,
                                            float* __restrict__ pn,
                                            const float* __restrict__ sim,
                                            float* __restrict__ accg) {
    int t = threadIdx.x;
    if (blockIdx.x == 128) {
        __shared__ float S[128 * 128];
        __shared__ float red[128];
        for (int i = t * 4; i < 16384; i += 512)
            *(float4*)&S[i] = *(const float4*)&sim[i];
        __syncthreads();
        float m = -3e38f, m2 = -3e38f;
        for (int j = 0; j < 128; j++) {
            m = fmaxf(m, S[t * 128 + j]);
            m2 = fmaxf(m2, S[j * 128 + t]);
        }
        float s = 0.0f, s2 = 0.0f;
        for (int j = 0; j < 128; j++) {
            s += expf(S[t * 128 + j] - m);
            s2 += expf(S[j * 128 + t] - m2);
        }
        float contrib = 2.0f * S[t * 128 + t] - (m + logf(s)) - (m2 + logf(s2));
        red[t] = contrib;
        __syncthreads();
        for (int o = 64; o > 0; o >>= 1) {
            if (t < o) red[t] += red[t + o];
            __syncthreads();
        }
        if (t == 0) accg[0] = -red[0] / 256.0f;
        return;
    }
    int b = blockIdx.x;
    int c = cols[b * 128 + t];
    float nv = rnV[b * 128 + t];
    float nt = rnT[b * 128 + c];
    float Cv = cost[((size_t)b * 128 + t) * 128 + c];
    // sum((V-T_c)^2) = |V|^2 + |T_c|^2 - 2 |V||T_c| cos,  cos = 1 - Cv
    float s = nv * nv + nt * nt - 2.0f * nv * nt * (1.0f - Cv);
#pragma unroll
    for (int off = 32; off > 0; off >>= 1) s += __shfl_xor(s, off);
    __shared__ float w2[2];
    if ((t & 63) == 0) w2[t >> 6] = s;
    __syncthreads();
    if (t == 0) pn[b] = w2[0] + w2[1];
}

// ---------------- finalize ----------------
__global__ __launch_bounds__(128) void k_final(const float* __restrict__ accg,
                                               const float* __restrict__ pn,
                                               const float* __restrict__ pg,
                                               float* __restrict__ out) {
    __shared__ float r1[128], r2[128];
    int t = threadIdx.x;
    r1[t] = pn[t];
    r2[t] = pg[t];
    __syncthreads();
    for (int o = 64; o > 0; o >>= 1) {
        if (t < o) { r1[t] += r1[t + o]; r2[t] += r2[t + o]; }
        __syncthreads();
    }
    if (t == 0) {
        float lg = accg[0];
        float ln = r1[0] / 16777216.0f;   // 128*128*1024
        float lgr = r2[0] / 2097152.0f;   // 128*128*128
        out[0] = lg + ln + lgr;
        out[1] = lg;
        out[2] = ln;
        out[3] = lgr;
    }
}

extern "C" void kernel_launch(void* const* d_in, const int* in_sizes, int n_in,
                              void* d_out, int out_size, void* d_ws, size_t ws_size,
                              hipStream_t stream) {
    const float* vg = (const float*)d_in[0];
    const float* tg = (const float*)d_in[1];
    const float* V  = (const float*)d_in[2];
    const float* T  = (const float*)d_in[3];
    const float* Av = (const float*)d_in[4];
    const float* At = (const float*)d_in[5];
    float* out = (float*)d_out;
    float* ws = (float*)d_ws;

    float* cost = ws + WS_COST;
    float* sim  = ws + WS_SIM;
    int*   cols = (int*)(ws + WS_COLS);
    float* rnV  = ws + WS_RNV;
    float* rnT  = ws + WS_RNT;
    float* pn   = ws + WS_PNODE;
    float* pg   = ws + WS_PGRAPH;
    float* acc  = ws + WS_ACC;

    k_cost<<<256, 256, 0, stream>>>(V, T, cost, rnV, rnT);
    k_main<<<258, 256, 0, stream>>>(cost, cols, vg, tg, sim, Av, At, pg);
    k_gn<<<129, 128, 0, stream>>>(rnV, rnT, cost, cols, pn, sim, acc);
    k_final<<<1, 128, 0, stream>>>(acc, pn, pg, out);
}

// Round 9
// 402.978 us; speedup vs baseline: 3.1114x; 1.0073x over previous
//
#include <hip/hip_runtime.h>
#include <hip/hip_fp16.h>
#include <math.h>

#define TEMPERATURE 0.07f

// ---------------- ws layout (float offsets) ----------------
#define WS_COST    0          // 128*128*128 = 2097152
#define WS_SIM     2097152    // 16384
#define WS_COLS    2113536    // 16384 ints
#define WS_RNV     2129920    // 16384 |V| row norms
#define WS_RNT     2146304    // 16384 |T| row norms
#define WS_PNODE   2162688    // 128 partials
#define WS_PGRAPH  2162816    // 128 partials
#define WS_ACC     2162944    // 16 floats

// =================== shared MFMA cosine-tile machinery ========================
typedef __attribute__((ext_vector_type(8))) short short8v;
typedef __attribute__((ext_vector_type(4))) float f32x4;

__device__ __forceinline__ short bf16rne(float f) {
    unsigned int u = __float_as_uint(f);
    u += 0x7FFFu + ((u >> 16) & 1u);
    return (short)(u >> 16);
}
__device__ __forceinline__ short8v cvt8s(const float* __restrict__ p, float& ssq) {
    float4 x = *(const float4*)p;
    float4 y = *(const float4*)(p + 4);
    ssq += x.x * x.x + x.y * x.y + x.z * x.z + x.w * x.w
         + y.x * y.x + y.y * y.y + y.z * y.z + y.w * y.w;
    short8v r;
    r[0] = bf16rne(x.x); r[1] = bf16rne(x.y);
    r[2] = bf16rne(x.z); r[3] = bf16rne(x.w);
    r[4] = bf16rne(y.x); r[5] = bf16rne(y.y);
    r[6] = bf16rne(y.z); r[7] = bf16rne(y.w);
    return r;
}

// 64x128 cosine tile (half selects which 64 rows). COSTMODE: out = 1-cos and
// export row norms. !COSTMODE: out = cos/TEMP (for sim).
template<bool COSTMODE>
__device__ __forceinline__ void cos_tile(const float* __restrict__ Vb,
                                         const float* __restrict__ Tb,
                                         int half, int tid,
                                         float* __restrict__ outp,
                                         float* __restrict__ rnV,
                                         float* __restrict__ rnT) {
    int w = tid >> 6;
    int lane = tid & 63;
    int n0 = half * 64 + (w >> 1) * 32;
    int m0 = (w & 1) * 64;
    int ar = lane & 15, kq = lane >> 4;
    float qA0 = 0.0f, qA1 = 0.0f, qB0 = 0.0f, qB1 = 0.0f, qB2 = 0.0f, qB3 = 0.0f;
    f32x4 zero = {0.0f, 0.0f, 0.0f, 0.0f};
    f32x4 acc[2][4];
#pragma unroll
    for (int i = 0; i < 2; i++)
#pragma unroll
        for (int j = 0; j < 4; j++) acc[i][j] = zero;

    for (int k0 = 0; k0 < 1024; k0 += 32) {
        int ko = k0 + kq * 8;
        short8v a0 = cvt8s(&Vb[(size_t)(n0 + ar) * 1024 + ko], qA0);
        short8v a1 = cvt8s(&Vb[(size_t)(n0 + 16 + ar) * 1024 + ko], qA1);
        short8v b0 = cvt8s(&Tb[(size_t)(m0 + ar) * 1024 + ko], qB0);
        short8v b1 = cvt8s(&Tb[(size_t)(m0 + 16 + ar) * 1024 + ko], qB1);
        short8v b2 = cvt8s(&Tb[(size_t)(m0 + 32 + ar) * 1024 + ko], qB2);
        short8v b3 = cvt8s(&Tb[(size_t)(m0 + 48 + ar) * 1024 + ko], qB3);
        acc[0][0] = __builtin_amdgcn_mfma_f32_16x16x32_bf16(a0, b0, acc[0][0], 0, 0, 0);
        acc[0][1] = __builtin_amdgcn_mfma_f32_16x16x32_bf16(a0, b1, acc[0][1], 0, 0, 0);
        acc[0][2] = __builtin_amdgcn_mfma_f32_16x16x32_bf16(a0, b2, acc[0][2], 0, 0, 0);
        acc[0][3] = __builtin_amdgcn_mfma_f32_16x16x32_bf16(a0, b3, acc[0][3], 0, 0, 0);
        acc[1][0] = __builtin_amdgcn_mfma_f32_16x16x32_bf16(a1, b0, acc[1][0], 0, 0, 0);
        acc[1][1] = __builtin_amdgcn_mfma_f32_16x16x32_bf16(a1, b1, acc[1][1], 0, 0, 0);
        acc[1][2] = __builtin_amdgcn_mfma_f32_16x16x32_bf16(a1, b2, acc[1][2], 0, 0, 0);
        acc[1][3] = __builtin_amdgcn_mfma_f32_16x16x32_bf16(a1, b3, acc[1][3], 0, 0, 0);
    }
    qA0 += __shfl_xor(qA0, 16); qA0 += __shfl_xor(qA0, 32);
    qA1 += __shfl_xor(qA1, 16); qA1 += __shfl_xor(qA1, 32);
    qB0 += __shfl_xor(qB0, 16); qB0 += __shfl_xor(qB0, 32);
    qB1 += __shfl_xor(qB1, 16); qB1 += __shfl_xor(qB1, 32);
    qB2 += __shfl_xor(qB2, 16); qB2 += __shfl_xor(qB2, 32);
    qB3 += __shfl_xor(qB3, 16); qB3 += __shfl_xor(qB3, 32);
    if (COSTMODE && kq == 0) {
        rnV[n0 + ar]      = sqrtf(qA0);
        rnV[n0 + 16 + ar] = sqrtf(qA1);
        rnT[m0 + ar]      = sqrtf(qB0);
        rnT[m0 + 16 + ar] = sqrtf(qB1);
        rnT[m0 + 32 + ar] = sqrtf(qB2);
        rnT[m0 + 48 + ar] = sqrtf(qB3);
    }
    float invA0 = 1.0f / fmaxf(sqrtf(qA0), 1e-12f);
    float invA1 = 1.0f / fmaxf(sqrtf(qA1), 1e-12f);
    float invB[4];
    invB[0] = 1.0f / fmaxf(sqrtf(qB0), 1e-12f);
    invB[1] = 1.0f / fmaxf(sqrtf(qB1), 1e-12f);
    invB[2] = 1.0f / fmaxf(sqrtf(qB2), 1e-12f);
    invB[3] = 1.0f / fmaxf(sqrtf(qB3), 1e-12f);
    // D layout: row = (lane>>4)*4 + r, col = lane&15
#pragma unroll
    for (int i = 0; i < 2; i++) {
        float ia[4];
#pragma unroll
        for (int r = 0; r < 4; r++)
            ia[r] = __shfl(i ? invA1 : invA0, kq * 4 + r);
#pragma unroll
        for (int j = 0; j < 4; j++)
#pragma unroll
            for (int r = 0; r < 4; r++) {
                int rowi = n0 + i * 16 + kq * 4 + r;
                int colj = m0 + j * 16 + ar;
                float cs = acc[i][j][r] * ia[r] * invB[j];
                outp[(size_t)rowi * 128 + colj] =
                    COSTMODE ? (1.0f - cs) : (cs * (1.0f / TEMPERATURE));
            }
    }
}

// ---------------- cost + row norms ----------------
__global__ __launch_bounds__(256) void k_cost(const float* __restrict__ V,
                                              const float* __restrict__ T,
                                              float* __restrict__ cost,
                                              float* __restrict__ rnV,
                                              float* __restrict__ rnT) {
    int b = blockIdx.x >> 1;
    int half = blockIdx.x & 1;
    cos_tile<true>(V + (size_t)b * 131072, T + (size_t)b * 131072, half, threadIdx.x,
                   cost + (size_t)b * 16384, rnV + b * 128, rnT + b * 128);
}

// =================== Hungarian helpers ========================================
#define HUNG_INF 3.0e38f
// column jitter: c'[i][j] = c[i][j] + j*JEPS. Column-only shifts add the SAME
// constant to every perfect matching -> optimal-assignment set preserved
// exactly, while argmin ties (fp16 quantization) are broken deterministically.
// JEPS = 2^-15 > key truncation step (2^-16 rel) so jittered cols stay distinct.
#define JEPS 3.0517578125e-05f

__device__ __forceinline__ int rdlane_i(int v, int l) {
    return __builtin_amdgcn_readlane(v, l);
}
__device__ __forceinline__ float rdlane_f(float v, int l) {
    return __int_as_float(__builtin_amdgcn_readlane(__float_as_int(v), l));
}

__device__ __forceinline__ unsigned int dpp_umin_wave(unsigned int x) {
    int o;
    o = __builtin_amdgcn_update_dpp(-1, (int)x, 0x111, 0xF, 0xF, false);
    x = (x < (unsigned int)o) ? x : (unsigned int)o;
    o = __builtin_amdgcn_update_dpp(-1, (int)x, 0x112, 0xF, 0xF, false);
    x = (x < (unsigned int)o) ? x : (unsigned int)o;
    o = __builtin_amdgcn_update_dpp(-1, (int)x, 0x114, 0xF, 0xF, false);
    x = (x < (unsigned int)o) ? x : (unsigned int)o;
    o = __builtin_amdgcn_update_dpp(-1, (int)x, 0x118, 0xF, 0xF, false);
    x = (x < (unsigned int)o) ? x : (unsigned int)o;
    o = __builtin_amdgcn_update_dpp(-1, (int)x, 0x142, 0xF, 0xF, false);
    x = (x < (unsigned int)o) ? x : (unsigned int)o;
    o = __builtin_amdgcn_update_dpp(-1, (int)x, 0x143, 0xF, 0xF, false);
    x = (x < (unsigned int)o) ? x : (unsigned int)o;
    return x;
}

// paired two-smallest DPP stage (exact at lane 63: merge windows are disjoint)
template<int CTRL>
__device__ __forceinline__ void dpp2min(unsigned int& a, unsigned int& b) {
    unsigned int ao = (unsigned int)__builtin_amdgcn_update_dpp(-1, (int)a, CTRL, 0xF, 0xF, false);
    unsigned int bo = (unsigned int)__builtin_amdgcn_update_dpp(-1, (int)b, CTRL, 0xF, 0xF, false);
    unsigned int hi = a > ao ? a : ao;
    a = a < ao ? a : ao;
    b = b < bo ? b : bo;
    b = b < hi ? b : hi;
}

__device__ __forceinline__ unsigned int pack_h2(float a, float b) {
    unsigned int ua = (unsigned int)__half_as_ushort(__float2half(a));
    unsigned int ub = (unsigned int)__half_as_ushort(__float2half(b));
    return ua | (ub << 16);
}
// jittered unpack (the ONLY way hungarian reads the cost matrix)
__device__ __forceinline__ float jlo(unsigned int u, int lane) {
    return __half2float(__ushort_as_half((unsigned short)(u & 0xFFFFu))) + (float)lane * JEPS;
}
__device__ __forceinline__ float jhi(unsigned int u, int lane) {
    return __half2float(__ushort_as_half((unsigned short)(u >> 16))) + (float)(lane + 64) * JEPS;
}
// sortable key: biased value bits (top 25) | column index (low 7). val >= -eps.
__device__ __forceinline__ unsigned int vkey(float v, int idx) {
    return (__float_as_uint(v + 1.0f) & 0xFFFFFF80u) | (unsigned int)idx;
}

// =================== uber-kernel: hungarian + sim + graph =====================
// blocks 0..127: LAPJV per batch problem (wave 0 after 256-thread staging)
// blocks 128..129: sim = cos(vg,tg)/TEMP via MFMA (two 64-row halves)
// blocks 130..257: graph-MSE partials (fill CUs idle during hungarian)
__global__ __launch_bounds__(256) void k_main(const float* __restrict__ cost,
                                              int* __restrict__ cols,
                                              const float* __restrict__ vg,
                                              const float* __restrict__ tg,
                                              float* __restrict__ sim,
                                              const float* __restrict__ Av,
                                              const float* __restrict__ At,
                                              float* __restrict__ pg) {
    int bid = blockIdx.x;
    int t = threadIdx.x;
    __shared__ unsigned int P[8192];     // 32 KB packed fp16 cost
    __shared__ int freelist[136];
    __shared__ float wsumg[4];

    if (bid >= 130) {                    // ---- graph MSE partial ----
        int idx = bid - 130;
        float s = 0.0f;
        for (int it = 0; it < 16; ++it) {
            size_t off = (((size_t)idx * 16 + it) * 256 + t) * 4;
            float4 a = *(const float4*)&Av[off];
            float4 bb = *(const float4*)&At[off];
            float dx = a.x - bb.x, dy = a.y - bb.y, dz = a.z - bb.z, dw = a.w - bb.w;
            s += dx * dx + dy * dy + dz * dz + dw * dw;
        }
#pragma unroll
        for (int off = 32; off > 0; off >>= 1) s += __shfl_xor(s, off);
        if ((t & 63) == 0) wsumg[t >> 6] = s;
        __syncthreads();
        if (t == 0) pg[idx] = wsumg[0] + wsumg[1] + wsumg[2] + wsumg[3];
        return;
    }
    if (bid >= 128) {                    // ---- sim via MFMA ----
        cos_tile<false>(vg, tg, bid - 128, t, sim, (float*)0, (float*)0);
        return;
    }

    // ---- hungarian: stage with all 256 threads, then wave 0 solves ----
    int b = bid;
    const float* C = cost + (size_t)b * 16384;
    for (int i = t; i < 8192; i += 256) {
        int r = i >> 6, l = i & 63;
        P[i] = pack_h2(C[r * 128 + l], C[r * 128 + 64 + l]);
    }
    __syncthreads();
    if (t >= 64) return;                 // no barriers beyond this point
    int lane = t;

    // ---- phase 1: column reduction (jittered) ----
    float vA = HUNG_INF, vB = HUNG_INF;
    int yA = 0, yB = 0;
    for (int r = 0; r < 128; ++r) {
        unsigned int pk = P[r * 64 + lane];
        float a = jlo(pk, lane), bb = jhi(pk, lane);
        if (a < vA) { vA = a; yA = r; }
        if (bb < vB) { vB = bb; yB = r; }
    }
    int p0 = -1, p1 = -1;     // row matched to col lane / lane+64
    int x0 = -1, x1 = -1;     // col matched to row lane / lane+64
    float u0 = 0.0f, u1 = 0.0f;
    for (int j = 127; j >= 0; --j) {
        int yi = rdlane_i(j >= 64 ? yB : yA, j & 63);
        int xi = rdlane_i(yi >= 64 ? x1 : x0, yi & 63);
        if (xi < 0) {
            if (lane == (yi & 63)) { if (yi < 64) x0 = j; else x1 = j; }
            if (lane == (j & 63)) { if (j < 64) p0 = yi; else p1 = yi; }
        }
    }

    // ---- phase 1.5: reduction transfer ----
    {
        unsigned int pkc = P[lane];
        for (int i = 0; i < 128; ++i) {
            unsigned int pkn = (i < 127) ? P[(i + 1) * 64 + lane] : 0u;
            int j1 = rdlane_i(i >= 64 ? x1 : x0, i & 63);
            if (j1 >= 0) {
                float rc0 = jlo(pkc, lane) - vA;
                float rc1 = jhi(pkc, lane) - vB;
                unsigned int k0 = (j1 < 64 && lane == j1) ? 0xFFFFFFFFu : vkey(rc0, lane);
                unsigned int k1 = (j1 >= 64 && lane == (j1 - 64)) ? 0xFFFFFFFFu : vkey(rc1, lane + 64);
                unsigned int km = dpp_umin_wave(k0 < k1 ? k0 : k1);
                unsigned int ka = (unsigned int)rdlane_i((int)km, 63);
                float min2 = __uint_as_float(ka & 0xFFFFFF80u) - 1.0f;
                if (lane == (j1 & 63)) { if (j1 < 64) vA -= min2; else vB -= min2; }
                if (lane == (i & 63)) { if (i < 64) u0 = min2; else u1 = min2; }
            }
            pkc = pkn;
        }
    }

    // ---- free-row list ----
    unsigned long long fm0 = __ballot(x0 < 0);
    unsigned long long fm1 = __ballot(x1 < 0);
    int half0 = __popcll(fm0);
    int nfree = half0 + __popcll(fm1);
    if (x0 < 0) freelist[__popcll(fm0 & ((1ull << lane) - 1))] = lane;
    if (x1 < 0) freelist[half0 + __popcll(fm1 & ((1ull << lane) - 1))] = lane + 64;

    // ---- phase 2: ARR x3, pending-register chaining + prefetched cost row ----
    for (int pass = 0; pass < 3 && nfree > 0; ++pass) {
        int cur = 0, nnew = 0, rr = 0;
        int pending = -1;
        unsigned int pkPre = 0;
        while (pending >= 0 || cur < nfree) {
            int fi;
            unsigned int pk;
            if (pending >= 0) { fi = pending; pk = pkPre; pending = -1; }
            else { fi = freelist[cur++]; pk = P[fi * 64 + lane]; }
            rr++;
            if (rr >= 600) {
                if (lane == 0) freelist[nnew] = fi;
                nnew++;
                continue;
            }
            float rc0 = jlo(pk, lane) - vA;
            float rc1 = jhi(pk, lane) - vB;
            unsigned int k0 = vkey(rc0, lane);
            unsigned int k1 = vkey(rc1, lane + 64);
            unsigned int a = k0 < k1 ? k0 : k1;
            unsigned int bk = k0 < k1 ? k1 : k0;
            dpp2min<0x111>(a, bk); dpp2min<0x112>(a, bk); dpp2min<0x114>(a, bk);
            dpp2min<0x118>(a, bk); dpp2min<0x142>(a, bk); dpp2min<0x143>(a, bk);
            unsigned int ka = (unsigned int)rdlane_i((int)a, 63);
            unsigned int kb = (unsigned int)rdlane_i((int)bk, 63);
            int j1 = (int)(ka & 127u);
            float vmin = __uint_as_float(ka & 0xFFFFFF80u) - 1.0f;
            float vsec = __uint_as_float(kb & 0xFFFFFF80u) - 1.0f;
            bool lowers = (ka & 0xFFFFFF80u) < (kb & 0xFFFFFF80u);
            int i0 = rdlane_i(j1 >= 64 ? p1 : p0, j1 & 63);
            if (lowers) {
                if (lane == (j1 & 63)) {
                    if (j1 < 64) vA -= (vsec - vmin); else vB -= (vsec - vmin);
                }
            } else if (i0 >= 0) {
                j1 = (int)(kb & 127u);
                i0 = rdlane_i(j1 >= 64 ? p1 : p0, j1 & 63);
            }
            if (i0 >= 0) {
                if (lowers) {
                    pending = i0;                       // reprocess next iteration
                    pkPre = P[i0 * 64 + lane];          // prefetch its cost row
                } else {
                    if (lane == 0) freelist[nnew] = i0; // defer to next pass
                    nnew++;
                }
            }
            if (lane == (j1 & 63)) { if (j1 < 64) p0 = fi; else p1 = fi; }
            if (lane == (fi & 63)) { if (fi < 64) u0 = vsec; else u1 = vsec; }
        }
        nfree = nnew;
    }

    // ---- phase 3: exact Dijkstra augmentation for remaining free rows ----
    for (int fx = 0; fx < nfree; ++fx) {
        int row = freelist[fx];
        float minv0 = HUNG_INF, minv1 = HUNG_INF;
        int way0 = 128, way1 = 128;
        bool used0 = false, used1 = false;
        bool intree0 = (row < 64) && (lane == row);
        bool intree1 = (row >= 64) && (lane == row - 64);
        int j0 = 128;
        int i0r = row;
        while (true) {
            float ui = rdlane_f(i0r >= 64 ? u1 : u0, i0r & 63);
            unsigned int pk = P[i0r * 64 + lane];
            float cur0 = jlo(pk, lane) - ui - vA;
            float cur1 = jhi(pk, lane) - ui - vB;
            if (!used0 && cur0 < minv0) { minv0 = cur0; way0 = j0; }
            if (!used1 && cur1 < minv1) { minv1 = cur1; way1 = j0; }
            float cand0 = used0 ? HUNG_INF : minv0;
            float cand1 = used1 ? HUNG_INF : minv1;
            unsigned int k0 = vkey(cand0, lane);
            unsigned int k1 = vkey(cand1, lane + 64);
            unsigned int km = dpp_umin_wave(k0 < k1 ? k0 : k1);
            unsigned int kmin = (unsigned int)rdlane_i((int)km, 63);
            int j1 = (int)(kmin & 127u);
            float delta = __uint_as_float(kmin & 0xFFFFFF80u) - 1.0f;
            if (used0) vA -= delta; else minv0 -= delta;
            if (used1) vB -= delta; else minv1 -= delta;
            if (intree0) u0 += delta;
            if (intree1) u1 += delta;
            int pj = rdlane_i(j1 >= 64 ? p1 : p0, j1 & 63);
            if (pj >= 0) {
                if (lane == (j1 & 63)) { if (j1 >= 64) used1 = true; else used0 = true; }
                if (lane == (pj & 63)) { if (pj < 64) intree0 = true; else intree1 = true; }
                j0 = j1;
                i0r = pj;
            } else {
                int j = j1;
                while (j != 128) {
                    int w = rdlane_i(j >= 64 ? way1 : way0, j & 63);
                    int pw = (w == 128) ? row : rdlane_i(w >= 64 ? p1 : p0, w & 63);
                    if (lane == (j & 63)) { if (j >= 64) p1 = pw; else p0 = pw; }
                    j = w;
                }
                break;
            }
        }
    }
    cols[b * 128 + p0] = lane;
    cols[b * 128 + p1] = lane + 64;
}

// ---------------- node MSE (reconstructed from norms+cost) + L_global ----------
// blocks 0..127: node partial for batch b. block 128: L_global.
__global__ __launch_bounds__(128) void k_gn(const float* __restrict__ rnV,
                                            const float* __restrict__ rnT,
                                            const float* __restrict__ cost,
                                            const int* __restrict__ cols,
                                            float* __restrict__ pn,
                                            const float* __restrict__ sim,
                                            float* __restrict__ accg) {
    int t = threadIdx.x;
    if (blockIdx.x == 128) {
        __shared__ float S[128 * 128];
        __shared__ float red[128];
        for (int i = t * 4; i < 16384; i += 512)
            *(float4*)&S[i] = *(const float4*)&sim[i];
        __syncthreads();
        float m = -3e38f, m2 = -3e38f;
        for (int j = 0; j < 128; j++) {
            m = fmaxf(m, S[t * 128 + j]);
            m2 = fmaxf(m2, S[j * 128 + t]);
        }
        float s = 0.0f, s2 = 0.0f;
        for (int j = 0; j < 128; j++) {
            s += expf(S[t * 128 + j] - m);
            s2 += expf(S[j * 128 + t] - m2);
        }
        float contrib = 2.0f * S[t * 128 + t] - (m + logf(s)) - (m2 + logf(s2));
        red[t] = contrib;
        __syncthreads();
        for (int o = 64; o > 0; o >>= 1) {
            if (t < o) red[t] += red[t + o];
            __syncthreads();
        }
        if (t == 0) accg[0] = -red[0] / 256.0f;
        return;
    }
    int b = blockIdx.x;
    int c = cols[b * 128 + t];
    float nv = rnV[b * 128 + t];
    float nt = rnT[b * 128 + c];
    float Cv = cost[((size_t)b * 128 + t) * 128 + c];
    // sum((V-T_c)^2) = |V|^2 + |T_c|^2 - 2 |V||T_c| cos,  cos = 1 - Cv
    float s = nv * nv + nt * nt - 2.0f * nv * nt * (1.0f - Cv);
#pragma unroll
    for (int off = 32; off > 0; off >>= 1) s += __shfl_xor(s, off);
    __shared__ float w2[2];
    if ((t & 63) == 0) w2[t >> 6] = s;
    __syncthreads();
    if (t == 0) pn[b] = w2[0] + w2[1];
}

// ---------------- finalize ----------------
__global__ __launch_bounds__(128) void k_final(const float* __restrict__ accg,
                                               const float* __restrict__ pn,
                                               const float* __restrict__ pg,
                                               float* __restrict__ out) {
    __shared__ float r1[128], r2[128];
    int t = threadIdx.x;
    r1[t] = pn[t];
    r2[t] = pg[t];
    __syncthreads();
    for (int o = 64; o > 0; o >>= 1) {
        if (t < o) { r1[t] += r1[t + o]; r2[t] += r2[t + o]; }
        __syncthreads();
    }
    if (t == 0) {
        float lg = accg[0];
        float ln = r1[0] / 16777216.0f;   // 128*128*1024
        float lgr = r2[0] / 2097152.0f;   // 128*128*128
        out[0] = lg + ln + lgr;
        out[1] = lg;
        out[2] = ln;
        out[3] = lgr;
    }
}

extern "C" void kernel_launch(void* const* d_in, const int* in_sizes, int n_in,
                              void* d_out, int out_size, void* d_ws, size_t ws_size,
                              hipStream_t stream) {
    const float* vg = (const float*)d_in[0];
    const float* tg = (const float*)d_in[1];
    const float* V  = (const float*)d_in[2];
    const float* T  = (const float*)d_in[3];
    const float* Av = (const float*)d_in[4];
    const float* At = (const float*)d_in[5];
    float* out = (float*)d_out;
    float* ws = (float*)d_ws;

    float* cost = ws + WS_COST;
    float* sim  = ws + WS_SIM;
    int*   cols = (int*)(ws + WS_COLS);
    float* rnV  = ws + WS_RNV;
    float* rnT  = ws + WS_RNT;
    float* pn   = ws + WS_PNODE;
    float* pg   = ws + WS_PGRAPH;
    float* acc  = ws + WS_ACC;

    k_cost<<<256, 256, 0, stream>>>(V, T, cost, rnV, rnT);
    k_main<<<258, 256, 0, stream>>>(cost, cols, vg, tg, sim, Av, At, pg);
    k_gn<<<129, 128, 0, stream>>>(rnV, rnT, cost, cols, pn, sim, acc);
    k_final<<<1, 128, 0, stream>>>(acc, pn, pg, out);
}